// Round 8
// baseline (189.002 us; speedup 1.0000x reference)
//
#include <hip/hip_runtime.h>
#include <math.h>

#define S_LEN 2048
#define DMODEL 1024
#define NH 16
#define DEPTH 64
#define BATCH 2
#define MTOT (BATCH * S_LEN) // 4096

typedef __attribute__((ext_vector_type(8))) short short8;
typedef __attribute__((ext_vector_type(4))) short short4v;
typedef __attribute__((ext_vector_type(4))) float floatx4;

typedef const __attribute__((address_space(1))) unsigned gas_u32;
typedef __attribute__((address_space(3))) unsigned las_u32;

__device__ __forceinline__ short f2bf(float f) {
    union { float f; unsigned u; } v; v.f = f;
    unsigned r = v.u + 0x7fffu + ((v.u >> 16) & 1u);
    return (short)(r >> 16);
}

__device__ __forceinline__ floatx4 mfma16(short8 a, short8 b, floatx4 c) {
    return __builtin_amdgcn_mfma_f32_16x16x32_bf16(a, b, c, 0, 0, 0);
}

// K=16 bf16 MFMA: A/B are 4 bf16 per lane (2 VGPRs). A: row=lane&15, k=(lane>>4)*4+e.
#if __has_builtin(__builtin_amdgcn_mfma_f32_16x16x16bf16_1k)
__device__ __forceinline__ floatx4 mfma16k16(short4v a, short4v b, floatx4 c) {
    return __builtin_amdgcn_mfma_f32_16x16x16bf16_1k(a, b, c, 0, 0, 0);
}
#else
__device__ __forceinline__ floatx4 mfma16k16(short4v a, short4v b, floatx4 c) {
    asm volatile("v_mfma_f32_16x16x16_bf16 %0, %1, %2, %0\n\ts_nop 7\n\ts_nop 7"
                 : "+v"(c) : "v"(a), "v"(b));
    return c;
}
#endif

// ---------------- convert x: fp32 -> bf16 ----------------
__global__ __launch_bounds__(256) void convert_x_kernel(const float* __restrict__ x,
                                                        short* __restrict__ xb) {
    int i = (blockIdx.x * 256 + threadIdx.x) * 4;
    float4 v = *(const float4*)(x + i);
    short4v o;
    o.x = f2bf(v.x); o.y = f2bf(v.y); o.z = f2bf(v.z); o.w = f2bf(v.w);
    *(short4v*)(xb + i) = o;
}

// ---------------- transpose+convert weights: (K,N) fp32 -> (N,K) bf16 ----------------
__global__ __launch_bounds__(256) void wt_kernel(const float* __restrict__ w0, const float* __restrict__ w1,
                                                 const float* __restrict__ w2, const float* __restrict__ w3,
                                                 short* __restrict__ o0, short* __restrict__ o1,
                                                 short* __restrict__ o2, short* __restrict__ o3) {
    const float* src; short* dst;
    switch (blockIdx.z) {
        case 0: src = w0; dst = o0; break;
        case 1: src = w1; dst = o1; break;
        case 2: src = w2; dst = o2; break;
        default: src = w3; dst = o3; break;
    }
    __shared__ float tile[32][33];
    int tx = threadIdx.x, ty = threadIdx.y;
    int c = blockIdx.x * 32 + tx;
    int r0 = blockIdx.y * 32;
#pragma unroll
    for (int i = 0; i < 4; i++)
        tile[ty + i * 8][tx] = src[(size_t)(r0 + ty + i * 8) * DMODEL + c];
    __syncthreads();
    int co = blockIdx.y * 32 + tx;
    int ro = blockIdx.x * 32;
#pragma unroll
    for (int i = 0; i < 4; i++)
        dst[(size_t)(ro + ty + i * 8) * DMODEL + co] = f2bf(tile[tx][ty + i * 8]);
}

// ---------------- shared GEMM mainloop: C(128x128) = A(MxK) * Bt(NxK)^T ----------------
__device__ __forceinline__ void gemm_core(const short* __restrict__ A,
                                          const short* __restrict__ Bt,
                                          int m0, int n0,
                                          short (*As)[72], short (*Bs)[72],
                                          floatx4 acc[4][4]) {
    const int t = threadIdx.x;
    const int lane = t & 63;
    const int w = t >> 6;
    const int wr = w >> 1, wc = w & 1;
    const int l15 = lane & 15, lhi = lane >> 4;
    const int lrow = t >> 3;        // 0..31
    const int lcol = (t & 7) * 8;   // 0..56

    for (int k0 = 0; k0 < DMODEL; k0 += 64) {
#pragma unroll
        for (int i = 0; i < 4; i++) {
            int row = i * 32 + lrow;
            *(short8*)&As[row][lcol] = *(const short8*)(A + (size_t)(m0 + row) * DMODEL + k0 + lcol);
            *(short8*)&Bs[row][lcol] = *(const short8*)(Bt + (size_t)(n0 + row) * DMODEL + k0 + lcol);
        }
        __syncthreads();
#pragma unroll
        for (int kk = 0; kk < 64; kk += 32) {
            short8 af[4], bf[4];
#pragma unroll
            for (int i = 0; i < 4; i++)
                af[i] = *(short8*)&As[wr * 64 + i * 16 + l15][kk + lhi * 8];
#pragma unroll
            for (int j = 0; j < 4; j++)
                bf[j] = *(short8*)&Bs[wc * 64 + j * 16 + l15][kk + lhi * 8];
#pragma unroll
            for (int i = 0; i < 4; i++)
#pragma unroll
                for (int j = 0; j < 4; j++)
                    acc[i][j] = mfma16(af[i], bf[j], acc[i][j]);
        }
        __syncthreads();
    }
}

// ---------------- QKV GEMM: out layouts per-head; V transposed; Q pre-scaled ----------------
__global__ __launch_bounds__(256) void gemm_qkv(const short* __restrict__ A,
                                                const short* __restrict__ wq, const short* __restrict__ wk,
                                                const short* __restrict__ wv,
                                                const float* __restrict__ bq, const float* __restrict__ bk,
                                                const float* __restrict__ bv,
                                                short* __restrict__ qh, short* __restrict__ kh,
                                                short* __restrict__ vt) {
    __shared__ short As[128][72];
    __shared__ short Bs[128][72];
    const int mode = blockIdx.z;
    const short* Bt = (mode == 0) ? wq : (mode == 1) ? wk : wv;
    const float* bias = (mode == 0) ? bq : (mode == 1) ? bk : bv;

    floatx4 acc[4][4];
    floatx4 z = {0.f, 0.f, 0.f, 0.f};
#pragma unroll
    for (int i = 0; i < 4; i++)
#pragma unroll
        for (int j = 0; j < 4; j++) acc[i][j] = z;

    const int m0 = blockIdx.y * 128, n0 = blockIdx.x * 128;
    gemm_core(A, Bt, m0, n0, As, Bs, acc);

    const int lane = threadIdx.x & 63;
    const int w = threadIdx.x >> 6;
    const int wr = w >> 1, wc = w & 1;
    const int l15 = lane & 15, lhi = lane >> 4;
    // fold 1/sqrt(depth) AND log2(e) into Q so attention uses exp2 directly
    const float qscale = (mode == 0) ? 0.125f * 1.44269504f : 1.0f;
#pragma unroll
    for (int i = 0; i < 4; i++) {
#pragma unroll
        for (int j = 0; j < 4; j++) {
            int n = n0 + wc * 64 + j * 16 + l15;
            float bv_ = bias[n];
            int h = n >> 6, d = n & 63;
            int mbase = m0 + wr * 64 + i * 16 + (lhi << 2);
#pragma unroll
            for (int r = 0; r < 4; r++) {
                int m = mbase + r;
                int b = m >> 11, s = m & 2047;
                short val = f2bf((acc[i][j][r] + bv_) * qscale);
                if (mode == 0)
                    qh[((size_t)(b * NH + h) * S_LEN + s) * DEPTH + d] = val;
                else if (mode == 1)
                    kh[((size_t)(b * NH + h) * S_LEN + s) * DEPTH + d] = val;
                else
                    vt[((size_t)(b * NH + h) * DEPTH + d) * S_LEN + s] = val;
            }
        }
    }
}

// ---------------- output projection GEMM: fp32 out ----------------
__global__ __launch_bounds__(256) void gemm_out(const short* __restrict__ A,
                                                const short* __restrict__ Bt,
                                                const float* __restrict__ bias,
                                                float* __restrict__ out) {
    __shared__ short As[128][72];
    __shared__ short Bs[128][72];
    floatx4 acc[4][4];
    floatx4 z = {0.f, 0.f, 0.f, 0.f};
#pragma unroll
    for (int i = 0; i < 4; i++)
#pragma unroll
        for (int j = 0; j < 4; j++) acc[i][j] = z;

    const int m0 = blockIdx.y * 128, n0 = blockIdx.x * 128;
    gemm_core(A, Bt, m0, n0, As, Bs, acc);

    const int lane = threadIdx.x & 63;
    const int w = threadIdx.x >> 6;
    const int wr = w >> 1, wc = w & 1;
    const int l15 = lane & 15, lhi = lane >> 4;
#pragma unroll
    for (int i = 0; i < 4; i++) {
#pragma unroll
        for (int j = 0; j < 4; j++) {
            int n = n0 + wc * 64 + j * 16 + l15;
            float bv_ = bias[n];
            int mbase = m0 + wr * 64 + i * 16 + (lhi << 2);
#pragma unroll
            for (int r = 0; r < 4; r++) {
                int m = mbase + r;
                out[(size_t)m * DMODEL + n] = acc[i][j][r] + bv_;
            }
        }
    }
}

// ---------------- flash attention v6: 2-wave blocks, defer-max, exp2 ----------------
// Block = 2 waves, 64 q-rows (32/wave, 2 qg streams); grid 32x32 = 1024 blocks
// (4 blocks/CU) for causal-triangle load balance. K/V staged per 64-key tile into
// LDS via global_load_lds (linear dest + inverse-XOR-swizzled source; XOR reads).
// Swapped QK^T -> in-register P -> K=16 PV. Online softmax in log2 domain
// (Q pre-scaled by 0.125*log2e). T13 defer-max: rescale only when row max grows
// > 12 (log2) -> skips 4 broadcast shuffles + rescale muls on ~every tile.

__device__ __forceinline__ void stage_kv(const short* __restrict__ kb_j0,  // kb + j0*DEPTH
                                         const short* __restrict__ vb, int j0,
                                         short* kt, short* vt_, int wid, int lane) {
#pragma unroll
    for (int s = 0; s < 4; s++) {
        const int seg = (s * 2 + wid) * 1024;        // byte segment of the 8KB tile
        const int p = seg + lane * 16;               // linear LDS byte position
        const int q = p ^ (((p >> 7) & 7) << 4);     // inverse-swizzled source offset
        // K rows are contiguous (stride 128B == row size) -> source byte = q
        __builtin_amdgcn_global_load_lds((gas_u32*)((const char*)kb_j0 + q),
                                         (las_u32*)((char*)kt + seg), 16, 0, 0);
        // V^T row stride = S_LEN*2 bytes
        const char* vsrc = (const char*)vb + (size_t)(q >> 7) * (S_LEN * 2) + j0 * 2 + (q & 127);
        __builtin_amdgcn_global_load_lds((gas_u32*)vsrc,
                                         (las_u32*)((char*)vt_ + seg), 16, 0, 0);
    }
}

__global__ __launch_bounds__(128, 2) void attn_kernel(const short* __restrict__ qh,
                                                      const short* __restrict__ kh,
                                                      const short* __restrict__ vt,
                                                      const float* __restrict__ pm,
                                                      short* __restrict__ ao) {
    __shared__ short kbuf[2][4096];
    __shared__ short vbuf[2][4096];
    const int lane = threadIdx.x & 63;
    const int wid = threadIdx.x >> 6;  // 0..1
    const int bh = blockIdx.y;
    const int b = bh >> 4, h = bh & 15;
    const int chunk = (int)gridDim.x - 1 - (int)blockIdx.x;  // heavy-first
    const int qb = chunk * 64;
    const int qwb = qb + wid * 32;
    const short* qbp = qh + (size_t)bh * S_LEN * DEPTH;
    const short* kb = kh + (size_t)bh * S_LEN * DEPTH;
    const short* vb = vt + (size_t)bh * DEPTH * S_LEN;
    const float* pmb = pm + b * S_LEN;
    const int l15 = lane & 15, lhi = lane >> 4;
    const int swz = (l15 & 7) << 4;

    short8 qf[2][2];
#pragma unroll
    for (int qg = 0; qg < 2; qg++)
#pragma unroll
        for (int c = 0; c < 2; c++)
            qf[qg][c] = *(const short8*)(qbp + (size_t)(qwb + qg * 16 + l15) * DEPTH + c * 32 + lhi * 8);

    float m_r[2] = {-1e30f, -1e30f};
    float l_part[2] = {0.f, 0.f};
    floatx4 oacc[2][4];
    floatx4 z = {0.f, 0.f, 0.f, 0.f};
#pragma unroll
    for (int qg = 0; qg < 2; qg++)
#pragma unroll
        for (int dt = 0; dt < 4; dt++) oacc[qg][dt] = z;

    const int NT = chunk + 1;  // key tiles 0 .. qb (diag)
    stage_kv(kb, vb, 0, kbuf[0], vbuf[0], wid, lane);
    __syncthreads();

    for (int t = 0; t < NT; t++) {
        const int cur = t & 1;
        if (t + 1 < NT)
            stage_kv(kb + (size_t)(t + 1) * 64 * DEPTH, vb, (t + 1) * 64,
                     kbuf[cur ^ 1], vbuf[cur ^ 1], wid, lane);
        const int j0 = t * 64;
        {
            const short* kt = kbuf[cur];
            const short* vtile = vbuf[cur];
            // ---- K frags from LDS (swizzled reads) ----
            short8 kf[4][2];
#pragma unroll
            for (int tt = 0; tt < 4; tt++)
#pragma unroll
                for (int c = 0; c < 2; c++) {
                    int off = (((tt * 16 + l15) * 128) + c * 64 + lhi * 16) ^ swz;
                    kf[tt][c] = *(const short8*)((const char*)kt + off);
                }
            // ---- QK^T (swapped): col=q, row=key ----
            floatx4 sacc[2][4];
#pragma unroll
            for (int qg = 0; qg < 2; qg++)
#pragma unroll
                for (int tt = 0; tt < 4; tt++) sacc[qg][tt] = z;
#pragma unroll
            for (int tt = 0; tt < 4; tt++)
#pragma unroll
                for (int c = 0; c < 2; c++) {
                    sacc[0][tt] = mfma16(kf[tt][c], qf[0][c], sacc[0][tt]);
                    sacc[1][tt] = mfma16(kf[tt][c], qf[1][c], sacc[1][tt]);
                }
            // ---- V frags from LDS (swizzled reads) ----
            short4v vf[4][4];
#pragma unroll
            for (int tt = 0; tt < 4; tt++)
#pragma unroll
                for (int dt = 0; dt < 4; dt++) {
                    int off = (((dt * 16 + l15) * 128) + tt * 32 + lhi * 8) ^ swz;
                    vf[tt][dt] = *(const short4v*)((const char*)vtile + off);
                }
            // ---- padding mask terms (log2 domain) ----
            float pd[16];
#pragma unroll
            for (int tt = 0; tt < 4; tt++) {
                float4 pmv = *(const float4*)(pmb + j0 + tt * 16 + lhi * 4);
                pd[tt * 4 + 0] = (1.f - pmv.x) * -1.44269504e9f;
                pd[tt * 4 + 1] = (1.f - pmv.y) * -1.44269504e9f;
                pd[tt * 4 + 2] = (1.f - pmv.z) * -1.44269504e9f;
                pd[tt * 4 + 3] = (1.f - pmv.w) * -1.44269504e9f;
            }
            // ---- per-qg online softmax (log2) + in-register PV ----
#pragma unroll
            for (int qg = 0; qg < 2; qg++) {
                const int q = qwb + qg * 16 + l15;
                // causal mask needed iff max key (j0+63) can exceed min q (qwb+qg*16)
                const bool domask = (j0 + 63 > qwb + qg * 16);
                float mx = -1e30f;
#pragma unroll
                for (int tt = 0; tt < 4; tt++)
#pragma unroll
                    for (int r = 0; r < 4; r++) {
                        float v = sacc[qg][tt][r] + pd[tt * 4 + r];
                        if (domask) {
                            int key = j0 + tt * 16 + lhi * 4 + r;
                            v = (key > q) ? -1e30f : v;
                        }
                        sacc[qg][tt][r] = v;
                        mx = fmaxf(mx, v);
                    }
                mx = fmaxf(mx, __shfl_xor(mx, 16, 64));
                mx = fmaxf(mx, __shfl_xor(mx, 32, 64));
                // T13 defer-max: only rescale when the row max materially grows
                if (!__all(mx <= m_r[qg] + 12.0f)) {
                    float mnew = fmaxf(m_r[qg], mx);
                    float sf = exp2f(m_r[qg] - mnew);
                    m_r[qg] = mnew;
                    l_part[qg] *= sf;
#pragma unroll
                    for (int r = 0; r < 4; r++) {
                        float sfr = __shfl(sf, lhi * 4 + r, 64);
#pragma unroll
                        for (int dt = 0; dt < 4; dt++) oacc[qg][dt][r] *= sfr;
                    }
                }
#pragma unroll
                for (int tt = 0; tt < 4; tt++) {
                    float p0 = exp2f(sacc[qg][tt][0] - m_r[qg]);
                    float p1 = exp2f(sacc[qg][tt][1] - m_r[qg]);
                    float p2 = exp2f(sacc[qg][tt][2] - m_r[qg]);
                    float p3 = exp2f(sacc[qg][tt][3] - m_r[qg]);
                    l_part[qg] += (p0 + p1) + (p2 + p3);
                    short4v af;
                    af.x = f2bf(p0);
                    af.y = f2bf(p1);
                    af.z = f2bf(p2);
                    af.w = f2bf(p3);
#pragma unroll
                    for (int dt = 0; dt < 4; dt++)
                        oacc[qg][dt] = mfma16k16(af, vf[tt][dt], oacc[qg][dt]);
                }
            }
        }
        // explicit drain (compiler emits this before s_barrier anyway; determinism insurance)
        asm volatile("s_waitcnt vmcnt(0)" ::: "memory");
        __syncthreads();
    }

    // ---- epilogue: reduce per-lane partial sums once ----
#pragma unroll
    for (int qg = 0; qg < 2; qg++) {
        float lsum = l_part[qg];
        lsum += __shfl_xor(lsum, 16, 64);
        lsum += __shfl_xor(lsum, 32, 64);
        float rinv[4];
#pragma unroll
        for (int r = 0; r < 4; r++)
            rinv[r] = 1.0f / __shfl(lsum, lhi * 4 + r, 64);
#pragma unroll
        for (int dt = 0; dt < 4; dt++) {
            int d = dt * 16 + l15;
#pragma unroll
            for (int r = 0; r < 4; r++) {
                int row = qwb + qg * 16 + lhi * 4 + r;
                float o = oacc[qg][dt][r] * rinv[r];
                ao[((size_t)(b * S_LEN) + row) * DMODEL + h * DEPTH + d] = f2bf(o);
            }
        }
    }
}

extern "C" void kernel_launch(void* const* d_in, const int* in_sizes, int n_in,
                              void* d_out, int out_size, void* d_ws, size_t ws_size,
                              hipStream_t stream) {
    const float* x    = (const float*)d_in[0];
    const float* pm   = (const float*)d_in[1];
    const float* wq_w = (const float*)d_in[2];
    const float* wq_b = (const float*)d_in[3];
    const float* wk_w = (const float*)d_in[4];
    const float* wk_b = (const float*)d_in[5];
    const float* wv_w = (const float*)d_in[6];
    const float* wv_b = (const float*)d_in[7];
    const float* wo_w = (const float*)d_in[8];
    const float* wo_b = (const float*)d_in[9];
    float* out = (float*)d_out;

    char* ws = (char*)d_ws;
    const size_t MB = 1024 * 1024;
    short* xb  = (short*)(ws);            // 8 MB : x bf16 (4096x1024)
    short* wqb = (short*)(ws + 8 * MB);   // 2 MB : wq^T bf16
    short* wkb = (short*)(ws + 10 * MB);
    short* wvb = (short*)(ws + 12 * MB);
    short* wob = (short*)(ws + 14 * MB);
    short* qh  = (short*)(ws + 16 * MB);  // 8 MB : Q (B,H,S,depth) bf16, pre-scaled by 0.125*log2e
    short* kh  = (short*)(ws + 24 * MB);  // 8 MB : K (B,H,S,depth) bf16
    short* vt  = (short*)(ws + 32 * MB);  // 8 MB : V^T (B,H,depth,S) bf16
    short* ao  = (short*)(ws + 40 * MB);  // 8 MB : attn out (B,S,D) bf16

    convert_x_kernel<<<4096, 256, 0, stream>>>(x, xb);
    wt_kernel<<<dim3(32, 32, 4), dim3(32, 8), 0, stream>>>(wq_w, wk_w, wv_w, wo_w,
                                                           wqb, wkb, wvb, wob);
    gemm_qkv<<<dim3(8, 32, 3), 256, 0, stream>>>(xb, wqb, wkb, wvb, wq_b, wk_b, wv_b,
                                                 qh, kh, vt);
    attn_kernel<<<dim3(32, 32), 128, 0, stream>>>(qh, kh, vt, pm, ao);
    gemm_out<<<dim3(8, 32), 256, 0, stream>>>(ao, wob, wo_b, out);
}

// Round 9
// 183.719 us; speedup vs baseline: 1.0288x; 1.0288x over previous
//
#include <hip/hip_runtime.h>
#include <math.h>

#define S_LEN 2048
#define DMODEL 1024
#define NH 16
#define DEPTH 64
#define BATCH 2
#define MTOT (BATCH * S_LEN) // 4096

typedef __attribute__((ext_vector_type(8))) short short8;
typedef __attribute__((ext_vector_type(4))) short short4v;
typedef __attribute__((ext_vector_type(4))) float floatx4;

typedef const __attribute__((address_space(1))) unsigned gas_u32;
typedef __attribute__((address_space(3))) unsigned las_u32;

__device__ __forceinline__ short f2bf(float f) {
    union { float f; unsigned u; } v; v.f = f;
    unsigned r = v.u + 0x7fffu + ((v.u >> 16) & 1u);
    return (short)(r >> 16);
}

__device__ __forceinline__ floatx4 mfma16(short8 a, short8 b, floatx4 c) {
    return __builtin_amdgcn_mfma_f32_16x16x32_bf16(a, b, c, 0, 0, 0);
}

// K=16 bf16 MFMA: A/B are 4 bf16 per lane (2 VGPRs). A: row=lane&15, k=(lane>>4)*4+e.
#if __has_builtin(__builtin_amdgcn_mfma_f32_16x16x16bf16_1k)
__device__ __forceinline__ floatx4 mfma16k16(short4v a, short4v b, floatx4 c) {
    return __builtin_amdgcn_mfma_f32_16x16x16bf16_1k(a, b, c, 0, 0, 0);
}
#else
__device__ __forceinline__ floatx4 mfma16k16(short4v a, short4v b, floatx4 c) {
    asm volatile("v_mfma_f32_16x16x16_bf16 %0, %1, %2, %0\n\ts_nop 7\n\ts_nop 7"
                 : "+v"(c) : "v"(a), "v"(b));
    return c;
}
#endif

// ---------------- convert x: fp32 -> bf16 ----------------
__global__ __launch_bounds__(256) void convert_x_kernel(const float* __restrict__ x,
                                                        short* __restrict__ xb) {
    int i = (blockIdx.x * 256 + threadIdx.x) * 4;
    float4 v = *(const float4*)(x + i);
    short4v o;
    o.x = f2bf(v.x); o.y = f2bf(v.y); o.z = f2bf(v.z); o.w = f2bf(v.w);
    *(short4v*)(xb + i) = o;
}

// ---------------- transpose+convert weights: (K,N) fp32 -> (N,K) bf16 ----------------
__global__ __launch_bounds__(256) void wt_kernel(const float* __restrict__ w0, const float* __restrict__ w1,
                                                 const float* __restrict__ w2, const float* __restrict__ w3,
                                                 short* __restrict__ o0, short* __restrict__ o1,
                                                 short* __restrict__ o2, short* __restrict__ o3) {
    const float* src; short* dst;
    switch (blockIdx.z) {
        case 0: src = w0; dst = o0; break;
        case 1: src = w1; dst = o1; break;
        case 2: src = w2; dst = o2; break;
        default: src = w3; dst = o3; break;
    }
    __shared__ float tile[32][33];
    int tx = threadIdx.x, ty = threadIdx.y;
    int c = blockIdx.x * 32 + tx;
    int r0 = blockIdx.y * 32;
#pragma unroll
    for (int i = 0; i < 4; i++)
        tile[ty + i * 8][tx] = src[(size_t)(r0 + ty + i * 8) * DMODEL + c];
    __syncthreads();
    int co = blockIdx.y * 32 + tx;
    int ro = blockIdx.x * 32;
#pragma unroll
    for (int i = 0; i < 4; i++)
        dst[(size_t)(ro + ty + i * 8) * DMODEL + co] = f2bf(tile[tx][ty + i * 8]);
}

// ---------------- shared GEMM mainloop: C(128x128) = A(MxK) * Bt(NxK)^T ----------------
__device__ __forceinline__ void gemm_core(const short* __restrict__ A,
                                          const short* __restrict__ Bt,
                                          int m0, int n0,
                                          short (*As)[72], short (*Bs)[72],
                                          floatx4 acc[4][4]) {
    const int t = threadIdx.x;
    const int lane = t & 63;
    const int w = t >> 6;
    const int wr = w >> 1, wc = w & 1;
    const int l15 = lane & 15, lhi = lane >> 4;
    const int lrow = t >> 3;        // 0..31
    const int lcol = (t & 7) * 8;   // 0..56

    for (int k0 = 0; k0 < DMODEL; k0 += 64) {
#pragma unroll
        for (int i = 0; i < 4; i++) {
            int row = i * 32 + lrow;
            *(short8*)&As[row][lcol] = *(const short8*)(A + (size_t)(m0 + row) * DMODEL + k0 + lcol);
            *(short8*)&Bs[row][lcol] = *(const short8*)(Bt + (size_t)(n0 + row) * DMODEL + k0 + lcol);
        }
        __syncthreads();
#pragma unroll
        for (int kk = 0; kk < 64; kk += 32) {
            short8 af[4], bf[4];
#pragma unroll
            for (int i = 0; i < 4; i++)
                af[i] = *(short8*)&As[wr * 64 + i * 16 + l15][kk + lhi * 8];
#pragma unroll
            for (int j = 0; j < 4; j++)
                bf[j] = *(short8*)&Bs[wc * 64 + j * 16 + l15][kk + lhi * 8];
#pragma unroll
            for (int i = 0; i < 4; i++)
#pragma unroll
                for (int j = 0; j < 4; j++)
                    acc[i][j] = mfma16(af[i], bf[j], acc[i][j]);
        }
        __syncthreads();
    }
}

// ---------------- QKV GEMM: out layouts per-head; V transposed; Q pre-scaled ----------------
__global__ __launch_bounds__(256) void gemm_qkv(const short* __restrict__ A,
                                                const short* __restrict__ wq, const short* __restrict__ wk,
                                                const short* __restrict__ wv,
                                                const float* __restrict__ bq, const float* __restrict__ bk,
                                                const float* __restrict__ bv,
                                                short* __restrict__ qh, short* __restrict__ kh,
                                                short* __restrict__ vt) {
    __shared__ short As[128][72];
    __shared__ short Bs[128][72];
    const int mode = blockIdx.z;
    const short* Bt = (mode == 0) ? wq : (mode == 1) ? wk : wv;
    const float* bias = (mode == 0) ? bq : (mode == 1) ? bk : bv;

    floatx4 acc[4][4];
    floatx4 z = {0.f, 0.f, 0.f, 0.f};
#pragma unroll
    for (int i = 0; i < 4; i++)
#pragma unroll
        for (int j = 0; j < 4; j++) acc[i][j] = z;

    const int m0 = blockIdx.y * 128, n0 = blockIdx.x * 128;
    gemm_core(A, Bt, m0, n0, As, Bs, acc);

    const int lane = threadIdx.x & 63;
    const int w = threadIdx.x >> 6;
    const int wr = w >> 1, wc = w & 1;
    const int l15 = lane & 15, lhi = lane >> 4;
    // fold 1/sqrt(depth) AND log2(e) into Q so attention uses exp2 directly
    const float qscale = (mode == 0) ? 0.125f * 1.44269504f : 1.0f;
#pragma unroll
    for (int i = 0; i < 4; i++) {
#pragma unroll
        for (int j = 0; j < 4; j++) {
            int n = n0 + wc * 64 + j * 16 + l15;
            float bv_ = bias[n];
            int h = n >> 6, d = n & 63;
            int mbase = m0 + wr * 64 + i * 16 + (lhi << 2);
#pragma unroll
            for (int r = 0; r < 4; r++) {
                int m = mbase + r;
                int b = m >> 11, s = m & 2047;
                short val = f2bf((acc[i][j][r] + bv_) * qscale);
                if (mode == 0)
                    qh[((size_t)(b * NH + h) * S_LEN + s) * DEPTH + d] = val;
                else if (mode == 1)
                    kh[((size_t)(b * NH + h) * S_LEN + s) * DEPTH + d] = val;
                else
                    vt[((size_t)(b * NH + h) * DEPTH + d) * S_LEN + s] = val;
            }
        }
    }
}

// ---------------- output projection GEMM: fp32 out ----------------
__global__ __launch_bounds__(256) void gemm_out(const short* __restrict__ A,
                                                const short* __restrict__ Bt,
                                                const float* __restrict__ bias,
                                                float* __restrict__ out) {
    __shared__ short As[128][72];
    __shared__ short Bs[128][72];
    floatx4 acc[4][4];
    floatx4 z = {0.f, 0.f, 0.f, 0.f};
#pragma unroll
    for (int i = 0; i < 4; i++)
#pragma unroll
        for (int j = 0; j < 4; j++) acc[i][j] = z;

    const int m0 = blockIdx.y * 128, n0 = blockIdx.x * 128;
    gemm_core(A, Bt, m0, n0, As, Bs, acc);

    const int lane = threadIdx.x & 63;
    const int w = threadIdx.x >> 6;
    const int wr = w >> 1, wc = w & 1;
    const int l15 = lane & 15, lhi = lane >> 4;
#pragma unroll
    for (int i = 0; i < 4; i++) {
#pragma unroll
        for (int j = 0; j < 4; j++) {
            int n = n0 + wc * 64 + j * 16 + l15;
            float bv_ = bias[n];
            int mbase = m0 + wr * 64 + i * 16 + (lhi << 2);
#pragma unroll
            for (int r = 0; r < 4; r++) {
                int m = mbase + r;
                out[(size_t)m * DMODEL + n] = acc[i][j][r] + bv_;
            }
        }
    }
}

// ---------------- flash attention v7: round-7 config + exp2 + shuffle-free defer-max ----------------
// Block = 4 waves, 128 q-rows (32/wave, 2 qg streams); grid 16x32 (round-7-proven).
// K/V staged per 64-key tile into LDS via global_load_lds (linear dest +
// inverse-XOR-swizzled source; XOR reads). Swapped QK^T -> in-register P -> K=16 PV.
// log2-domain softmax (Q pre-scaled by 0.125*log2e). T13 defer-max with the row-max
// shuffles MOVED INSIDE the rescale branch: the __all() check works on per-lane maxes,
// so the common path has ZERO cross-lane ops.

__device__ __forceinline__ void stage_kv(const short* __restrict__ kb_j0,  // kb + j0*DEPTH
                                         const short* __restrict__ vb, int j0,
                                         short* kt, short* vt_, int wid, int lane) {
#pragma unroll
    for (int s = 0; s < 2; s++) {
        const int seg = (s * 4 + wid) * 1024;        // byte segment of the 8KB tile
        const int p = seg + lane * 16;               // linear LDS byte position
        const int q = p ^ (((p >> 7) & 7) << 4);     // inverse-swizzled source offset
        // K rows are contiguous (stride 128B == row size) -> source byte = q
        __builtin_amdgcn_global_load_lds((gas_u32*)((const char*)kb_j0 + q),
                                         (las_u32*)((char*)kt + seg), 16, 0, 0);
        // V^T row stride = S_LEN*2 bytes
        const char* vsrc = (const char*)vb + (size_t)(q >> 7) * (S_LEN * 2) + j0 * 2 + (q & 127);
        __builtin_amdgcn_global_load_lds((gas_u32*)vsrc,
                                         (las_u32*)((char*)vt_ + seg), 16, 0, 0);
    }
}

__global__ __launch_bounds__(256, 2) void attn_kernel(const short* __restrict__ qh,
                                                      const short* __restrict__ kh,
                                                      const short* __restrict__ vt,
                                                      const float* __restrict__ pm,
                                                      short* __restrict__ ao) {
    __shared__ short kbuf[2][4096];
    __shared__ short vbuf[2][4096];
    const int lane = threadIdx.x & 63;
    const int wid = threadIdx.x >> 6;  // 0..3
    const int bh = blockIdx.y;
    const int b = bh >> 4, h = bh & 15;
    const int chunk = (int)gridDim.x - 1 - (int)blockIdx.x;  // heavy-first
    const int qb = chunk * 128;
    const int qwb = qb + wid * 32;
    const short* qbp = qh + (size_t)bh * S_LEN * DEPTH;
    const short* kb = kh + (size_t)bh * S_LEN * DEPTH;
    const short* vb = vt + (size_t)bh * DEPTH * S_LEN;
    const float* pmb = pm + b * S_LEN;
    const int l15 = lane & 15, lhi = lane >> 4;
    const int swz = (l15 & 7) << 4;

    short8 qf[2][2];
#pragma unroll
    for (int qg = 0; qg < 2; qg++)
#pragma unroll
        for (int c = 0; c < 2; c++)
            qf[qg][c] = *(const short8*)(qbp + (size_t)(qwb + qg * 16 + l15) * DEPTH + c * 32 + lhi * 8);

    float m_r[2] = {-1e30f, -1e30f};
    float l_part[2] = {0.f, 0.f};
    floatx4 oacc[2][4];
    floatx4 z = {0.f, 0.f, 0.f, 0.f};
#pragma unroll
    for (int qg = 0; qg < 2; qg++)
#pragma unroll
        for (int dt = 0; dt < 4; dt++) oacc[qg][dt] = z;

    const int NT = 2 * chunk + 2;  // key tiles 0 .. qb+64
    stage_kv(kb, vb, 0, kbuf[0], vbuf[0], wid, lane);
    __syncthreads();

    for (int t = 0; t < NT; t++) {
        const int cur = t & 1;
        if (t + 1 < NT)
            stage_kv(kb + (size_t)(t + 1) * 64 * DEPTH, vb, (t + 1) * 64,
                     kbuf[cur ^ 1], vbuf[cur ^ 1], wid, lane);
        const int j0 = t * 64;
        if (j0 <= qwb + 31) {  // wave-uniform: skip fully-masked tiles (barriers still hit)
            const short* kt = kbuf[cur];
            const short* vtile = vbuf[cur];
            // ---- K frags from LDS (swizzled reads) ----
            short8 kf[4][2];
#pragma unroll
            for (int tt = 0; tt < 4; tt++)
#pragma unroll
                for (int c = 0; c < 2; c++) {
                    int off = (((tt * 16 + l15) * 128) + c * 64 + lhi * 16) ^ swz;
                    kf[tt][c] = *(const short8*)((const char*)kt + off);
                }
            // ---- QK^T (swapped): col=q, row=key ----
            floatx4 sacc[2][4];
#pragma unroll
            for (int qg = 0; qg < 2; qg++)
#pragma unroll
                for (int tt = 0; tt < 4; tt++) sacc[qg][tt] = z;
#pragma unroll
            for (int tt = 0; tt < 4; tt++)
#pragma unroll
                for (int c = 0; c < 2; c++) {
                    sacc[0][tt] = mfma16(kf[tt][c], qf[0][c], sacc[0][tt]);
                    sacc[1][tt] = mfma16(kf[tt][c], qf[1][c], sacc[1][tt]);
                }
            // ---- V frags from LDS (swizzled reads) ----
            short4v vf[4][4];
#pragma unroll
            for (int tt = 0; tt < 4; tt++)
#pragma unroll
                for (int dt = 0; dt < 4; dt++) {
                    int off = (((dt * 16 + l15) * 128) + tt * 32 + lhi * 8) ^ swz;
                    vf[tt][dt] = *(const short4v*)((const char*)vtile + off);
                }
            // ---- padding mask terms (log2 domain) ----
            float pd[16];
#pragma unroll
            for (int tt = 0; tt < 4; tt++) {
                float4 pmv = *(const float4*)(pmb + j0 + tt * 16 + lhi * 4);
                pd[tt * 4 + 0] = (1.f - pmv.x) * -1.44269504e9f;
                pd[tt * 4 + 1] = (1.f - pmv.y) * -1.44269504e9f;
                pd[tt * 4 + 2] = (1.f - pmv.z) * -1.44269504e9f;
                pd[tt * 4 + 3] = (1.f - pmv.w) * -1.44269504e9f;
            }
            // ---- per-qg online softmax (log2) + in-register PV ----
#pragma unroll
            for (int qg = 0; qg < 2; qg++) {
                const int q = qwb + qg * 16 + l15;
                // causal mask needed iff max key (j0+63) can exceed min q (qwb+qg*16)
                const bool domask = (j0 + 63 > qwb + qg * 16);
                float mx = -1e30f;
#pragma unroll
                for (int tt = 0; tt < 4; tt++)
#pragma unroll
                    for (int r = 0; r < 4; r++) {
                        float v = sacc[qg][tt][r] + pd[tt * 4 + r];
                        if (domask) {
                            int key = j0 + tt * 16 + lhi * 4 + r;
                            v = (key > q) ? -1e30f : v;
                        }
                        sacc[qg][tt][r] = v;
                        mx = fmaxf(mx, v);
                    }
                // T13 defer-max, shuffle-free common path: __all on per-lane maxes
                // tests "global row-max grew > 12" without any cross-lane reduce.
                if (!__all(mx <= m_r[qg] + 12.0f)) {
                    mx = fmaxf(mx, __shfl_xor(mx, 16, 64));
                    mx = fmaxf(mx, __shfl_xor(mx, 32, 64));
                    float mnew = fmaxf(m_r[qg], mx);
                    float sf = exp2f(m_r[qg] - mnew);
                    m_r[qg] = mnew;
                    l_part[qg] *= sf;
#pragma unroll
                    for (int r = 0; r < 4; r++) {
                        float sfr = __shfl(sf, lhi * 4 + r, 64);
#pragma unroll
                        for (int dt = 0; dt < 4; dt++) oacc[qg][dt][r] *= sfr;
                    }
                }
#pragma unroll
                for (int tt = 0; tt < 4; tt++) {
                    float p0 = exp2f(sacc[qg][tt][0] - m_r[qg]);
                    float p1 = exp2f(sacc[qg][tt][1] - m_r[qg]);
                    float p2 = exp2f(sacc[qg][tt][2] - m_r[qg]);
                    float p3 = exp2f(sacc[qg][tt][3] - m_r[qg]);
                    l_part[qg] += (p0 + p1) + (p2 + p3);
                    short4v af;
                    af.x = f2bf(p0);
                    af.y = f2bf(p1);
                    af.z = f2bf(p2);
                    af.w = f2bf(p3);
#pragma unroll
                    for (int dt = 0; dt < 4; dt++)
                        oacc[qg][dt] = mfma16k16(af, vf[tt][dt], oacc[qg][dt]);
                }
            }
        }
        // explicit drain (compiler emits this before s_barrier anyway; determinism insurance)
        asm volatile("s_waitcnt vmcnt(0)" ::: "memory");
        __syncthreads();
    }

    // ---- epilogue: reduce per-lane partial sums once ----
#pragma unroll
    for (int qg = 0; qg < 2; qg++) {
        float lsum = l_part[qg];
        lsum += __shfl_xor(lsum, 16, 64);
        lsum += __shfl_xor(lsum, 32, 64);
        float rinv[4];
#pragma unroll
        for (int r = 0; r < 4; r++)
            rinv[r] = 1.0f / __shfl(lsum, lhi * 4 + r, 64);
#pragma unroll
        for (int dt = 0; dt < 4; dt++) {
            int d = dt * 16 + l15;
#pragma unroll
            for (int r = 0; r < 4; r++) {
                int row = qwb + qg * 16 + lhi * 4 + r;
                float o = oacc[qg][dt][r] * rinv[r];
                ao[((size_t)(b * S_LEN) + row) * DMODEL + h * DEPTH + d] = f2bf(o);
            }
        }
    }
}

extern "C" void kernel_launch(void* const* d_in, const int* in_sizes, int n_in,
                              void* d_out, int out_size, void* d_ws, size_t ws_size,
                              hipStream_t stream) {
    const float* x    = (const float*)d_in[0];
    const float* pm   = (const float*)d_in[1];
    const float* wq_w = (const float*)d_in[2];
    const float* wq_b = (const float*)d_in[3];
    const float* wk_w = (const float*)d_in[4];
    const float* wk_b = (const float*)d_in[5];
    const float* wv_w = (const float*)d_in[6];
    const float* wv_b = (const float*)d_in[7];
    const float* wo_w = (const float*)d_in[8];
    const float* wo_b = (const float*)d_in[9];
    float* out = (float*)d_out;

    char* ws = (char*)d_ws;
    const size_t MB = 1024 * 1024;
    short* xb  = (short*)(ws);            // 8 MB : x bf16 (4096x1024)
    short* wqb = (short*)(ws + 8 * MB);   // 2 MB : wq^T bf16
    short* wkb = (short*)(ws + 10 * MB);
    short* wvb = (short*)(ws + 12 * MB);
    short* wob = (short*)(ws + 14 * MB);
    short* qh  = (short*)(ws + 16 * MB);  // 8 MB : Q (B,H,S,depth) bf16, pre-scaled by 0.125*log2e
    short* kh  = (short*)(ws + 24 * MB);  // 8 MB : K (B,H,S,depth) bf16
    short* vt  = (short*)(ws + 32 * MB);  // 8 MB : V^T (B,H,depth,S) bf16
    short* ao  = (short*)(ws + 40 * MB);  // 8 MB : attn out (B,S,D) bf16

    convert_x_kernel<<<4096, 256, 0, stream>>>(x, xb);
    wt_kernel<<<dim3(32, 32, 4), dim3(32, 8), 0, stream>>>(wq_w, wk_w, wv_w, wo_w,
                                                           wqb, wkb, wvb, wob);
    gemm_qkv<<<dim3(8, 32, 3), 256, 0, stream>>>(xb, wqb, wkb, wvb, wq_b, wk_b, wv_b,
                                                 qh, kh, vt);
    attn_kernel<<<dim3(16, 32), 256, 0, stream>>>(qh, kh, vt, pm, ao);
    gemm_out<<<dim3(8, 32), 256, 0, stream>>>(ao, wob, wo_b, out);
}

// Round 10
// 147.366 us; speedup vs baseline: 1.2825x; 1.2467x over previous
//
#include <hip/hip_runtime.h>
#include <math.h>

#define S_LEN 2048
#define DMODEL 1024
#define NH 16
#define DEPTH 64
#define BATCH 2
#define MTOT (BATCH * S_LEN) // 4096

typedef __attribute__((ext_vector_type(8))) short short8;
typedef __attribute__((ext_vector_type(4))) short short4v;
typedef __attribute__((ext_vector_type(4))) float floatx4;

typedef const __attribute__((address_space(1))) unsigned gas_u32;
typedef __attribute__((address_space(3))) unsigned las_u32;

__device__ __forceinline__ short f2bf(float f) {
    union { float f; unsigned u; } v; v.f = f;
    unsigned r = v.u + 0x7fffu + ((v.u >> 16) & 1u);
    return (short)(r >> 16);
}

__device__ __forceinline__ floatx4 mfma16(short8 a, short8 b, floatx4 c) {
    return __builtin_amdgcn_mfma_f32_16x16x32_bf16(a, b, c, 0, 0, 0);
}

// K=16 bf16 MFMA: A/B are 4 bf16 per lane (2 VGPRs). A: row=lane&15, k=(lane>>4)*4+e.
#if __has_builtin(__builtin_amdgcn_mfma_f32_16x16x16bf16_1k)
__device__ __forceinline__ floatx4 mfma16k16(short4v a, short4v b, floatx4 c) {
    return __builtin_amdgcn_mfma_f32_16x16x16bf16_1k(a, b, c, 0, 0, 0);
}
#else
__device__ __forceinline__ floatx4 mfma16k16(short4v a, short4v b, floatx4 c) {
    asm volatile("v_mfma_f32_16x16x16_bf16 %0, %1, %2, %0\n\ts_nop 7\n\ts_nop 7"
                 : "+v"(c) : "v"(a), "v"(b));
    return c;
}
#endif

// ---------------- convert x: fp32 -> bf16 ----------------
__global__ __launch_bounds__(256) void convert_x_kernel(const float* __restrict__ x,
                                                        short* __restrict__ xb) {
    int i = (blockIdx.x * 256 + threadIdx.x) * 4;
    float4 v = *(const float4*)(x + i);
    short4v o;
    o.x = f2bf(v.x); o.y = f2bf(v.y); o.z = f2bf(v.z); o.w = f2bf(v.w);
    *(short4v*)(xb + i) = o;
}

// ---------------- transpose+convert weights: (K,N) fp32 -> (N,K) bf16 ----------------
__global__ __launch_bounds__(256) void wt_kernel(const float* __restrict__ w0, const float* __restrict__ w1,
                                                 const float* __restrict__ w2, const float* __restrict__ w3,
                                                 short* __restrict__ o0, short* __restrict__ o1,
                                                 short* __restrict__ o2, short* __restrict__ o3) {
    const float* src; short* dst;
    switch (blockIdx.z) {
        case 0: src = w0; dst = o0; break;
        case 1: src = w1; dst = o1; break;
        case 2: src = w2; dst = o2; break;
        default: src = w3; dst = o3; break;
    }
    __shared__ float tile[32][33];
    int tx = threadIdx.x, ty = threadIdx.y;
    int c = blockIdx.x * 32 + tx;
    int r0 = blockIdx.y * 32;
#pragma unroll
    for (int i = 0; i < 4; i++)
        tile[ty + i * 8][tx] = src[(size_t)(r0 + ty + i * 8) * DMODEL + c];
    __syncthreads();
    int co = blockIdx.y * 32 + tx;
    int ro = blockIdx.x * 32;
#pragma unroll
    for (int i = 0; i < 4; i++)
        dst[(size_t)(ro + ty + i * 8) * DMODEL + co] = f2bf(tile[tx][ty + i * 8]);
}

// ---------------- GEMM v2: global_load_lds staged, XOR-swizzled, double-buffered ----------------
// Stages [128][64]-bf16 tiles (16KB) of A and Bt per K-step. Linear LDS dest +
// inverse-XOR-swizzled global source (the attn-proven involution on byte bits[6:4]
// keyed by LDS row&7); reads XOR back -> ~2-way conflicts (free).
__device__ __forceinline__ void stage_tile(const short* __restrict__ src, int row0, int k0,
                                           short* dstLds, int tid) {
#pragma unroll
    for (int s = 0; s < 4; s++) {
        const int p = s * 4096 + tid * 16;           // linear LDS byte position
        const int q = p ^ (((p >> 7) & 7) << 4);     // inverse-swizzled tile byte
        const char* srcp = (const char*)src + (size_t)(row0 + (q >> 7)) * (DMODEL * 2)
                         + k0 * 2 + (q & 127);
        __builtin_amdgcn_global_load_lds((gas_u32*)srcp,
                                         (las_u32*)((char*)dstLds + p), 16, 0, 0);
    }
}

__device__ __forceinline__ void gemm_core(const short* __restrict__ A,
                                          const short* __restrict__ Bt,
                                          int m0, int n0,
                                          short* Ab0, short* Ab1, short* Bb0, short* Bb1,
                                          floatx4 acc[4][4]) {
    const int tid = threadIdx.x;
    const int lane = tid & 63;
    const int w = tid >> 6;
    const int wr = w >> 1, wc = w & 1;
    const int l15 = lane & 15, lhi = lane >> 4;
    const int swz = (l15 & 7) << 4;

    stage_tile(A, m0, 0, Ab0, tid);
    stage_tile(Bt, n0, 0, Bb0, tid);
    asm volatile("s_waitcnt vmcnt(0)" ::: "memory");
    __syncthreads();

    for (int ks = 0; ks < 16; ks++) {
        const char* Ac = (const char*)((ks & 1) ? Ab1 : Ab0);
        const char* Bc = (const char*)((ks & 1) ? Bb1 : Bb0);
        if (ks < 15) {
            stage_tile(A, m0, (ks + 1) * 64, (ks & 1) ? Ab0 : Ab1, tid);
            stage_tile(Bt, n0, (ks + 1) * 64, (ks & 1) ? Bb0 : Bb1, tid);
        }
#pragma unroll
        for (int kkb = 0; kkb < 128; kkb += 64) {   // byte offset of 32-element K-slice
            short8 af[4], bf[4];
#pragma unroll
            for (int i = 0; i < 4; i++) {
                int row = wr * 64 + i * 16 + l15;
                af[i] = *(const short8*)(Ac + ((row * 128 + kkb + lhi * 16) ^ swz));
            }
#pragma unroll
            for (int j = 0; j < 4; j++) {
                int row = wc * 64 + j * 16 + l15;
                bf[j] = *(const short8*)(Bc + ((row * 128 + kkb + lhi * 16) ^ swz));
            }
#pragma unroll
            for (int i = 0; i < 4; i++)
#pragma unroll
                for (int j = 0; j < 4; j++)
                    acc[i][j] = mfma16(af[i], bf[j], acc[i][j]);
        }
        asm volatile("s_waitcnt vmcnt(0)" ::: "memory");
        __syncthreads();
    }
}

// ---------------- QKV GEMM: out layouts per-head; V transposed; Q pre-scaled ----------------
__global__ __launch_bounds__(256) void gemm_qkv(const short* __restrict__ A,
                                                const short* __restrict__ wq, const short* __restrict__ wk,
                                                const short* __restrict__ wv,
                                                const float* __restrict__ bq, const float* __restrict__ bk,
                                                const float* __restrict__ bv,
                                                short* __restrict__ qh, short* __restrict__ kh,
                                                short* __restrict__ vt) {
    __shared__ __align__(16) short Ab[2][8192];
    __shared__ __align__(16) short Bb[2][8192];
    const int mode = blockIdx.z;
    const short* Bt = (mode == 0) ? wq : (mode == 1) ? wk : wv;
    const float* bias = (mode == 0) ? bq : (mode == 1) ? bk : bv;

    floatx4 acc[4][4];
    floatx4 z = {0.f, 0.f, 0.f, 0.f};
#pragma unroll
    for (int i = 0; i < 4; i++)
#pragma unroll
        for (int j = 0; j < 4; j++) acc[i][j] = z;

    const int m0 = blockIdx.y * 128, n0 = blockIdx.x * 128;
    gemm_core(A, Bt, m0, n0, Ab[0], Ab[1], Bb[0], Bb[1], acc);

    const int lane = threadIdx.x & 63;
    const int w = threadIdx.x >> 6;
    const int wr = w >> 1, wc = w & 1;
    const int l15 = lane & 15, lhi = lane >> 4;
    const float qscale = (mode == 0) ? 0.125f : 1.0f;  // fold 1/sqrt(depth) into Q
#pragma unroll
    for (int i = 0; i < 4; i++) {
#pragma unroll
        for (int j = 0; j < 4; j++) {
            int n = n0 + wc * 64 + j * 16 + l15;
            float bv_ = bias[n];
            int h = n >> 6, d = n & 63;
            int mbase = m0 + wr * 64 + i * 16 + (lhi << 2);
#pragma unroll
            for (int r = 0; r < 4; r++) {
                int m = mbase + r;
                int b = m >> 11, s = m & 2047;
                short val = f2bf((acc[i][j][r] + bv_) * qscale);
                if (mode == 0)
                    qh[((size_t)(b * NH + h) * S_LEN + s) * DEPTH + d] = val;
                else if (mode == 1)
                    kh[((size_t)(b * NH + h) * S_LEN + s) * DEPTH + d] = val;
                else
                    vt[((size_t)(b * NH + h) * DEPTH + d) * S_LEN + s] = val;
            }
        }
    }
}

// ---------------- output projection GEMM: fp32 out ----------------
__global__ __launch_bounds__(256) void gemm_out(const short* __restrict__ A,
                                                const short* __restrict__ Bt,
                                                const float* __restrict__ bias,
                                                float* __restrict__ out) {
    __shared__ __align__(16) short Ab[2][8192];
    __shared__ __align__(16) short Bb[2][8192];
    floatx4 acc[4][4];
    floatx4 z = {0.f, 0.f, 0.f, 0.f};
#pragma unroll
    for (int i = 0; i < 4; i++)
#pragma unroll
        for (int j = 0; j < 4; j++) acc[i][j] = z;

    const int m0 = blockIdx.y * 128, n0 = blockIdx.x * 128;
    gemm_core(A, Bt, m0, n0, Ab[0], Ab[1], Bb[0], Bb[1], acc);

    const int lane = threadIdx.x & 63;
    const int w = threadIdx.x >> 6;
    const int wr = w >> 1, wc = w & 1;
    const int l15 = lane & 15, lhi = lane >> 4;
#pragma unroll
    for (int i = 0; i < 4; i++) {
#pragma unroll
        for (int j = 0; j < 4; j++) {
            int n = n0 + wc * 64 + j * 16 + l15;
            float bv_ = bias[n];
            int mbase = m0 + wr * 64 + i * 16 + (lhi << 2);
#pragma unroll
            for (int r = 0; r < 4; r++) {
                int m = mbase + r;
                out[(size_t)m * DMODEL + n] = acc[i][j][r] + bv_;
            }
        }
    }
}

// ---------------- flash attention v8: round-7 math + chunk-paired balance ----------------
// 256 blocks (8 pairs x 32 bh), one per CU. Each block runs the full round-7 flash
// loop TWICE sequentially: chunk p (2p+2 key tiles) then chunk 15-p (2(15-p)+2) ->
// 34 tiles per block, constant -> zero causal-tail imbalance. Inner math is the
// round-7-proven version: __expf, always-rescale, branch-free.

__device__ __forceinline__ void stage_kv(const short* __restrict__ kb_j0,  // kb + j0*DEPTH
                                         const short* __restrict__ vb, int j0,
                                         short* kt, short* vt_, int wid, int lane) {
#pragma unroll
    for (int s = 0; s < 2; s++) {
        const int seg = (s * 4 + wid) * 1024;        // byte segment of the 8KB tile
        const int p = seg + lane * 16;               // linear LDS byte position
        const int q = p ^ (((p >> 7) & 7) << 4);     // inverse-swizzled source offset
        __builtin_amdgcn_global_load_lds((gas_u32*)((const char*)kb_j0 + q),
                                         (las_u32*)((char*)kt + seg), 16, 0, 0);
        const char* vsrc = (const char*)vb + (size_t)(q >> 7) * (S_LEN * 2) + j0 * 2 + (q & 127);
        __builtin_amdgcn_global_load_lds((gas_u32*)vsrc,
                                         (las_u32*)((char*)vt_ + seg), 16, 0, 0);
    }
}

__global__ __launch_bounds__(256, 2) void attn_kernel(const short* __restrict__ qh,
                                                      const short* __restrict__ kh,
                                                      const short* __restrict__ vt,
                                                      const float* __restrict__ pm,
                                                      short* __restrict__ ao) {
    __shared__ short kbuf[2][4096];
    __shared__ short vbuf[2][4096];
    const int lane = threadIdx.x & 63;
    const int wid = threadIdx.x >> 6;  // 0..3
    const int bh = blockIdx.y;
    const int b = bh >> 4, h = bh & 15;
    const short* qbp = qh + (size_t)bh * S_LEN * DEPTH;
    const short* kb = kh + (size_t)bh * S_LEN * DEPTH;
    const short* vb = vt + (size_t)bh * DEPTH * S_LEN;
    const float* pmb = pm + b * S_LEN;
    const int l15 = lane & 15, lhi = lane >> 4;
    const int swz = (l15 & 7) << 4;

    for (int ph = 0; ph < 2; ph++) {
        const int chunk = (ph == 0) ? (int)blockIdx.x : (15 - (int)blockIdx.x);
        const int qwb = chunk * 128 + wid * 32;

        short8 qf[2][2];
#pragma unroll
        for (int qg = 0; qg < 2; qg++)
#pragma unroll
            for (int c = 0; c < 2; c++)
                qf[qg][c] = *(const short8*)(qbp + (size_t)(qwb + qg * 16 + l15) * DEPTH + c * 32 + lhi * 8);

        float m_r[2] = {-1e30f, -1e30f};
        float l_part[2] = {0.f, 0.f};
        floatx4 oacc[2][4];
        floatx4 z = {0.f, 0.f, 0.f, 0.f};
#pragma unroll
        for (int qg = 0; qg < 2; qg++)
#pragma unroll
            for (int dt = 0; dt < 4; dt++) oacc[qg][dt] = z;

        const int NT = 2 * chunk + 2;  // key tiles 0 .. chunk*128+64
        stage_kv(kb, vb, 0, kbuf[0], vbuf[0], wid, lane);
        __syncthreads();

        for (int t = 0; t < NT; t++) {
            const int cur = t & 1;
            if (t + 1 < NT)
                stage_kv(kb + (size_t)(t + 1) * 64 * DEPTH, vb, (t + 1) * 64,
                         kbuf[cur ^ 1], vbuf[cur ^ 1], wid, lane);
            const int j0 = t * 64;
            if (j0 <= qwb + 31) {  // wave-uniform: skip fully-masked tiles (barriers still hit)
                const short* kt = kbuf[cur];
                const short* vtile = vbuf[cur];
                short8 kf[4][2];
#pragma unroll
                for (int tt = 0; tt < 4; tt++)
#pragma unroll
                    for (int c = 0; c < 2; c++) {
                        int off = (((tt * 16 + l15) * 128) + c * 64 + lhi * 16) ^ swz;
                        kf[tt][c] = *(const short8*)((const char*)kt + off);
                    }
                floatx4 sacc[2][4];
#pragma unroll
                for (int qg = 0; qg < 2; qg++)
#pragma unroll
                    for (int tt = 0; tt < 4; tt++) sacc[qg][tt] = z;
#pragma unroll
                for (int tt = 0; tt < 4; tt++)
#pragma unroll
                    for (int c = 0; c < 2; c++) {
                        sacc[0][tt] = mfma16(kf[tt][c], qf[0][c], sacc[0][tt]);
                        sacc[1][tt] = mfma16(kf[tt][c], qf[1][c], sacc[1][tt]);
                    }
                short4v vf[4][4];
#pragma unroll
                for (int tt = 0; tt < 4; tt++)
#pragma unroll
                    for (int dt = 0; dt < 4; dt++) {
                        int off = (((dt * 16 + l15) * 128) + tt * 32 + lhi * 8) ^ swz;
                        vf[tt][dt] = *(const short4v*)((const char*)vtile + off);
                    }
                float pd[16];
#pragma unroll
                for (int tt = 0; tt < 4; tt++) {
                    float4 pmv = *(const float4*)(pmb + j0 + tt * 16 + lhi * 4);
                    pd[tt * 4 + 0] = (1.f - pmv.x) * -1e9f;
                    pd[tt * 4 + 1] = (1.f - pmv.y) * -1e9f;
                    pd[tt * 4 + 2] = (1.f - pmv.z) * -1e9f;
                    pd[tt * 4 + 3] = (1.f - pmv.w) * -1e9f;
                }
#pragma unroll
                for (int qg = 0; qg < 2; qg++) {
                    const int q = qwb + qg * 16 + l15;
                    const bool domask = (j0 + 63 > qwb + qg * 16);
                    float mx = -1e30f;
#pragma unroll
                    for (int tt = 0; tt < 4; tt++)
#pragma unroll
                        for (int r = 0; r < 4; r++) {
                            float v = sacc[qg][tt][r] + pd[tt * 4 + r];
                            if (domask) {
                                int key = j0 + tt * 16 + lhi * 4 + r;
                                v = (key > q) ? -1e30f : v;
                            }
                            sacc[qg][tt][r] = v;
                            mx = fmaxf(mx, v);
                        }
                    mx = fmaxf(mx, __shfl_xor(mx, 16, 64));
                    mx = fmaxf(mx, __shfl_xor(mx, 32, 64));
                    float mnew = fmaxf(m_r[qg], mx);
                    float sf = __expf(m_r[qg] - mnew);
                    m_r[qg] = mnew;
                    l_part[qg] *= sf;
#pragma unroll
                    for (int r = 0; r < 4; r++) {
                        float sfr = __shfl(sf, lhi * 4 + r, 64);
#pragma unroll
                        for (int dt = 0; dt < 4; dt++) oacc[qg][dt][r] *= sfr;
                    }
#pragma unroll
                    for (int tt = 0; tt < 4; tt++) {
                        float p0 = __expf(sacc[qg][tt][0] - m_r[qg]);
                        float p1 = __expf(sacc[qg][tt][1] - m_r[qg]);
                        float p2 = __expf(sacc[qg][tt][2] - m_r[qg]);
                        float p3 = __expf(sacc[qg][tt][3] - m_r[qg]);
                        l_part[qg] += (p0 + p1) + (p2 + p3);
                        short4v af;
                        af.x = f2bf(p0);
                        af.y = f2bf(p1);
                        af.z = f2bf(p2);
                        af.w = f2bf(p3);
#pragma unroll
                        for (int dt = 0; dt < 4; dt++)
                            oacc[qg][dt] = mfma16k16(af, vf[tt][dt], oacc[qg][dt]);
                    }
                }
            }
            asm volatile("s_waitcnt vmcnt(0)" ::: "memory");
            __syncthreads();
        }

        // ---- epilogue for this phase ----
#pragma unroll
        for (int qg = 0; qg < 2; qg++) {
            float lsum = l_part[qg];
            lsum += __shfl_xor(lsum, 16, 64);
            lsum += __shfl_xor(lsum, 32, 64);
            float rinv[4];
#pragma unroll
            for (int r = 0; r < 4; r++)
                rinv[r] = 1.0f / __shfl(lsum, lhi * 4 + r, 64);
#pragma unroll
            for (int dt = 0; dt < 4; dt++) {
                int d = dt * 16 + l15;
#pragma unroll
                for (int r = 0; r < 4; r++) {
                    int row = qwb + qg * 16 + lhi * 4 + r;
                    float o = oacc[qg][dt][r] * rinv[r];
                    ao[((size_t)(b * S_LEN) + row) * DMODEL + h * DEPTH + d] = f2bf(o);
                }
            }
        }
    }
}

extern "C" void kernel_launch(void* const* d_in, const int* in_sizes, int n_in,
                              void* d_out, int out_size, void* d_ws, size_t ws_size,
                              hipStream_t stream) {
    const float* x    = (const float*)d_in[0];
    const float* pm   = (const float*)d_in[1];
    const float* wq_w = (const float*)d_in[2];
    const float* wq_b = (const float*)d_in[3];
    const float* wk_w = (const float*)d_in[4];
    const float* wk_b = (const float*)d_in[5];
    const float* wv_w = (const float*)d_in[6];
    const float* wv_b = (const float*)d_in[7];
    const float* wo_w = (const float*)d_in[8];
    const float* wo_b = (const float*)d_in[9];
    float* out = (float*)d_out;

    char* ws = (char*)d_ws;
    const size_t MB = 1024 * 1024;
    short* xb  = (short*)(ws);            // 8 MB : x bf16 (4096x1024)
    short* wqb = (short*)(ws + 8 * MB);   // 2 MB : wq^T bf16
    short* wkb = (short*)(ws + 10 * MB);
    short* wvb = (short*)(ws + 12 * MB);
    short* wob = (short*)(ws + 14 * MB);
    short* qh  = (short*)(ws + 16 * MB);  // 8 MB : Q (B,H,S,depth) bf16, pre-scaled by 0.125
    short* kh  = (short*)(ws + 24 * MB);  // 8 MB : K (B,H,S,depth) bf16
    short* vt  = (short*)(ws + 32 * MB);  // 8 MB : V^T (B,H,depth,S) bf16
    short* ao  = (short*)(ws + 40 * MB);  // 8 MB : attn out (B,S,D) bf16

    convert_x_kernel<<<4096, 256, 0, stream>>>(x, xb);
    wt_kernel<<<dim3(32, 32, 4), dim3(32, 8), 0, stream>>>(wq_w, wk_w, wv_w, wo_w,
                                                           wqb, wkb, wvb, wob);
    gemm_qkv<<<dim3(8, 32, 3), 256, 0, stream>>>(xb, wqb, wkb, wvb, wq_b, wk_b, wv_b,
                                                 qh, kh, vt);
    attn_kernel<<<dim3(8, 32), 256, 0, stream>>>(qh, kh, vt, pm, ao);
    gemm_out<<<dim3(8, 32), 256, 0, stream>>>(ao, wob, wo_b, out);
}

// Round 11
// 143.000 us; speedup vs baseline: 1.3217x; 1.0305x over previous
//
#include <hip/hip_runtime.h>
#include <math.h>

#define S_LEN 2048
#define DMODEL 1024
#define NH 16
#define DEPTH 64
#define BATCH 2
#define MTOT (BATCH * S_LEN) // 4096

typedef __attribute__((ext_vector_type(8))) short short8;
typedef __attribute__((ext_vector_type(4))) short short4v;
typedef __attribute__((ext_vector_type(4))) float floatx4;

typedef const __attribute__((address_space(1))) unsigned gas_u32;
typedef __attribute__((address_space(3))) unsigned las_u32;

__device__ __forceinline__ short f2bf(float f) {
    union { float f; unsigned u; } v; v.f = f;
    unsigned r = v.u + 0x7fffu + ((v.u >> 16) & 1u);
    return (short)(r >> 16);
}

__device__ __forceinline__ floatx4 mfma16(short8 a, short8 b, floatx4 c) {
    return __builtin_amdgcn_mfma_f32_16x16x32_bf16(a, b, c, 0, 0, 0);
}

// K=16 bf16 MFMA: A/B are 4 bf16 per lane (2 VGPRs). A: row=lane&15, k=(lane>>4)*4+e.
#if __has_builtin(__builtin_amdgcn_mfma_f32_16x16x16bf16_1k)
__device__ __forceinline__ floatx4 mfma16k16(short4v a, short4v b, floatx4 c) {
    return __builtin_amdgcn_mfma_f32_16x16x16bf16_1k(a, b, c, 0, 0, 0);
}
#else
__device__ __forceinline__ floatx4 mfma16k16(short4v a, short4v b, floatx4 c) {
    asm volatile("v_mfma_f32_16x16x16_bf16 %0, %1, %2, %0\n\ts_nop 7\n\ts_nop 7"
                 : "+v"(c) : "v"(a), "v"(b));
    return c;
}
#endif

// ---------------- convert x: fp32 -> bf16 ----------------
__global__ __launch_bounds__(256) void convert_x_kernel(const float* __restrict__ x,
                                                        short* __restrict__ xb) {
    int i = (blockIdx.x * 256 + threadIdx.x) * 4;
    float4 v = *(const float4*)(x + i);
    short4v o;
    o.x = f2bf(v.x); o.y = f2bf(v.y); o.z = f2bf(v.z); o.w = f2bf(v.w);
    *(short4v*)(xb + i) = o;
}

// ---------------- transpose+convert weights: (K,N) fp32 -> (N,K) bf16 ----------------
__global__ __launch_bounds__(256) void wt_kernel(const float* __restrict__ w0, const float* __restrict__ w1,
                                                 const float* __restrict__ w2, const float* __restrict__ w3,
                                                 short* __restrict__ o0, short* __restrict__ o1,
                                                 short* __restrict__ o2, short* __restrict__ o3) {
    const float* src; short* dst;
    switch (blockIdx.z) {
        case 0: src = w0; dst = o0; break;
        case 1: src = w1; dst = o1; break;
        case 2: src = w2; dst = o2; break;
        default: src = w3; dst = o3; break;
    }
    __shared__ float tile[32][33];
    int tx = threadIdx.x, ty = threadIdx.y;
    int c = blockIdx.x * 32 + tx;
    int r0 = blockIdx.y * 32;
#pragma unroll
    for (int i = 0; i < 4; i++)
        tile[ty + i * 8][tx] = src[(size_t)(r0 + ty + i * 8) * DMODEL + c];
    __syncthreads();
    int co = blockIdx.y * 32 + tx;
    int ro = blockIdx.x * 32;
#pragma unroll
    for (int i = 0; i < 4; i++)
        dst[(size_t)(ro + ty + i * 8) * DMODEL + co] = f2bf(tile[tx][ty + i * 8]);
}

// ---------------- GEMM v2: global_load_lds staged, XOR-swizzled, double-buffered ----------------
__device__ __forceinline__ void stage_tile(const short* __restrict__ src, int row0, int k0,
                                           short* dstLds, int tid) {
#pragma unroll
    for (int s = 0; s < 4; s++) {
        const int p = s * 4096 + tid * 16;           // linear LDS byte position
        const int q = p ^ (((p >> 7) & 7) << 4);     // inverse-swizzled tile byte
        const char* srcp = (const char*)src + (size_t)(row0 + (q >> 7)) * (DMODEL * 2)
                         + k0 * 2 + (q & 127);
        __builtin_amdgcn_global_load_lds((gas_u32*)srcp,
                                         (las_u32*)((char*)dstLds + p), 16, 0, 0);
    }
}

__device__ __forceinline__ void gemm_core(const short* __restrict__ A,
                                          const short* __restrict__ Bt,
                                          int m0, int n0,
                                          short* Ab0, short* Ab1, short* Bb0, short* Bb1,
                                          floatx4 acc[4][4]) {
    const int tid = threadIdx.x;
    const int lane = tid & 63;
    const int w = tid >> 6;
    const int wr = w >> 1, wc = w & 1;
    const int l15 = lane & 15, lhi = lane >> 4;
    const int swz = (l15 & 7) << 4;

    stage_tile(A, m0, 0, Ab0, tid);
    stage_tile(Bt, n0, 0, Bb0, tid);
    asm volatile("s_waitcnt vmcnt(0)" ::: "memory");
    __syncthreads();

    for (int ks = 0; ks < 16; ks++) {
        const char* Ac = (const char*)((ks & 1) ? Ab1 : Ab0);
        const char* Bc = (const char*)((ks & 1) ? Bb1 : Bb0);
        if (ks < 15) {
            stage_tile(A, m0, (ks + 1) * 64, (ks & 1) ? Ab0 : Ab1, tid);
            stage_tile(Bt, n0, (ks + 1) * 64, (ks & 1) ? Bb0 : Bb1, tid);
        }
#pragma unroll
        for (int kkb = 0; kkb < 128; kkb += 64) {   // byte offset of 32-element K-slice
            short8 af[4], bf[4];
#pragma unroll
            for (int i = 0; i < 4; i++) {
                int row = wr * 64 + i * 16 + l15;
                af[i] = *(const short8*)(Ac + ((row * 128 + kkb + lhi * 16) ^ swz));
            }
#pragma unroll
            for (int j = 0; j < 4; j++) {
                int row = wc * 64 + j * 16 + l15;
                bf[j] = *(const short8*)(Bc + ((row * 128 + kkb + lhi * 16) ^ swz));
            }
#pragma unroll
            for (int i = 0; i < 4; i++)
#pragma unroll
                for (int j = 0; j < 4; j++)
                    acc[i][j] = mfma16(af[i], bf[j], acc[i][j]);
        }
        asm volatile("s_waitcnt vmcnt(0)" ::: "memory");
        __syncthreads();
    }
}

// ---------------- QKV GEMM: out layouts per-head; V transposed; Q pre-scaled ----------------
__global__ __launch_bounds__(256) void gemm_qkv(const short* __restrict__ A,
                                                const short* __restrict__ wq, const short* __restrict__ wk,
                                                const short* __restrict__ wv,
                                                const float* __restrict__ bq, const float* __restrict__ bk,
                                                const float* __restrict__ bv,
                                                short* __restrict__ qh, short* __restrict__ kh,
                                                short* __restrict__ vt) {
    __shared__ __align__(16) short Ab[2][8192];
    __shared__ __align__(16) short Bb[2][8192];
    const int mode = blockIdx.z;
    const short* Bt = (mode == 0) ? wq : (mode == 1) ? wk : wv;
    const float* bias = (mode == 0) ? bq : (mode == 1) ? bk : bv;

    floatx4 acc[4][4];
    floatx4 z = {0.f, 0.f, 0.f, 0.f};
#pragma unroll
    for (int i = 0; i < 4; i++)
#pragma unroll
        for (int j = 0; j < 4; j++) acc[i][j] = z;

    const int m0 = blockIdx.y * 128, n0 = blockIdx.x * 128;
    gemm_core(A, Bt, m0, n0, Ab[0], Ab[1], Bb[0], Bb[1], acc);

    const int lane = threadIdx.x & 63;
    const int w = threadIdx.x >> 6;
    const int wr = w >> 1, wc = w & 1;
    const int l15 = lane & 15, lhi = lane >> 4;
    const float qscale = (mode == 0) ? 0.125f : 1.0f;  // fold 1/sqrt(depth) into Q
#pragma unroll
    for (int i = 0; i < 4; i++) {
#pragma unroll
        for (int j = 0; j < 4; j++) {
            int n = n0 + wc * 64 + j * 16 + l15;
            float bv_ = bias[n];
            int h = n >> 6, d = n & 63;
            int mbase = m0 + wr * 64 + i * 16 + (lhi << 2);
#pragma unroll
            for (int r = 0; r < 4; r++) {
                int m = mbase + r;
                int b = m >> 11, s = m & 2047;
                short val = f2bf((acc[i][j][r] + bv_) * qscale);
                if (mode == 0)
                    qh[((size_t)(b * NH + h) * S_LEN + s) * DEPTH + d] = val;
                else if (mode == 1)
                    kh[((size_t)(b * NH + h) * S_LEN + s) * DEPTH + d] = val;
                else
                    vt[((size_t)(b * NH + h) * DEPTH + d) * S_LEN + s] = val;
            }
        }
    }
}

// ---------------- output projection GEMM: fp32 out ----------------
__global__ __launch_bounds__(256) void gemm_out(const short* __restrict__ A,
                                                const short* __restrict__ Bt,
                                                const float* __restrict__ bias,
                                                float* __restrict__ out) {
    __shared__ __align__(16) short Ab[2][8192];
    __shared__ __align__(16) short Bb[2][8192];
    floatx4 acc[4][4];
    floatx4 z = {0.f, 0.f, 0.f, 0.f};
#pragma unroll
    for (int i = 0; i < 4; i++)
#pragma unroll
        for (int j = 0; j < 4; j++) acc[i][j] = z;

    const int m0 = blockIdx.y * 128, n0 = blockIdx.x * 128;
    gemm_core(A, Bt, m0, n0, Ab[0], Ab[1], Bb[0], Bb[1], acc);

    const int lane = threadIdx.x & 63;
    const int w = threadIdx.x >> 6;
    const int wr = w >> 1, wc = w & 1;
    const int l15 = lane & 15, lhi = lane >> 4;
#pragma unroll
    for (int i = 0; i < 4; i++) {
#pragma unroll
        for (int j = 0; j < 4; j++) {
            int n = n0 + wc * 64 + j * 16 + l15;
            float bv_ = bias[n];
            int mbase = m0 + wr * 64 + i * 16 + (lhi << 2);
#pragma unroll
            for (int r = 0; r < 4; r++) {
                int m = mbase + r;
                out[(size_t)m * DMODEL + n] = acc[i][j][r] + bv_;
            }
        }
    }
}

// ---------------- flash attention v9: chunk-paired + XCD-local K/V ----------------
// Grid (bh=32, pair=8): linear block id = bh + 32*pair -> XCD = bh%8, so all 8
// pair-blocks of one head map to ONE XCD; 4 heads/XCD = 2MB K/V resident in the
// 4MB per-XCD L2 (was: pair%8 -> 8 XCDs x 16MB demand -> thrash, FETCH 71MB).
// Everything else identical to round-10 (round-7-proven inner math).

__device__ __forceinline__ void stage_kv(const short* __restrict__ kb_j0,  // kb + j0*DEPTH
                                         const short* __restrict__ vb, int j0,
                                         short* kt, short* vt_, int wid, int lane) {
#pragma unroll
    for (int s = 0; s < 2; s++) {
        const int seg = (s * 4 + wid) * 1024;        // byte segment of the 8KB tile
        const int p = seg + lane * 16;               // linear LDS byte position
        const int q = p ^ (((p >> 7) & 7) << 4);     // inverse-swizzled source offset
        __builtin_amdgcn_global_load_lds((gas_u32*)((const char*)kb_j0 + q),
                                         (las_u32*)((char*)kt + seg), 16, 0, 0);
        const char* vsrc = (const char*)vb + (size_t)(q >> 7) * (S_LEN * 2) + j0 * 2 + (q & 127);
        __builtin_amdgcn_global_load_lds((gas_u32*)vsrc,
                                         (las_u32*)((char*)vt_ + seg), 16, 0, 0);
    }
}

__global__ __launch_bounds__(256, 2) void attn_kernel(const short* __restrict__ qh,
                                                      const short* __restrict__ kh,
                                                      const short* __restrict__ vt,
                                                      const float* __restrict__ pm,
                                                      short* __restrict__ ao) {
    __shared__ short kbuf[2][4096];
    __shared__ short vbuf[2][4096];
    const int lane = threadIdx.x & 63;
    const int wid = threadIdx.x >> 6;  // 0..3
    const int bh = blockIdx.x;         // bh fastest -> same-head blocks share an XCD
    const int pair = blockIdx.y;       // 0..7
    const int b = bh >> 4, h = bh & 15;
    const short* qbp = qh + (size_t)bh * S_LEN * DEPTH;
    const short* kb = kh + (size_t)bh * S_LEN * DEPTH;
    const short* vb = vt + (size_t)bh * DEPTH * S_LEN;
    const float* pmb = pm + b * S_LEN;
    const int l15 = lane & 15, lhi = lane >> 4;
    const int swz = (l15 & 7) << 4;

    for (int ph = 0; ph < 2; ph++) {
        const int chunk = (ph == 0) ? pair : (15 - pair);
        const int qwb = chunk * 128 + wid * 32;

        short8 qf[2][2];
#pragma unroll
        for (int qg = 0; qg < 2; qg++)
#pragma unroll
            for (int c = 0; c < 2; c++)
                qf[qg][c] = *(const short8*)(qbp + (size_t)(qwb + qg * 16 + l15) * DEPTH + c * 32 + lhi * 8);

        float m_r[2] = {-1e30f, -1e30f};
        float l_part[2] = {0.f, 0.f};
        floatx4 oacc[2][4];
        floatx4 z = {0.f, 0.f, 0.f, 0.f};
#pragma unroll
        for (int qg = 0; qg < 2; qg++)
#pragma unroll
            for (int dt = 0; dt < 4; dt++) oacc[qg][dt] = z;

        const int NT = 2 * chunk + 2;  // key tiles 0 .. chunk*128+64
        stage_kv(kb, vb, 0, kbuf[0], vbuf[0], wid, lane);
        __syncthreads();

        for (int t = 0; t < NT; t++) {
            const int cur = t & 1;
            if (t + 1 < NT)
                stage_kv(kb + (size_t)(t + 1) * 64 * DEPTH, vb, (t + 1) * 64,
                         kbuf[cur ^ 1], vbuf[cur ^ 1], wid, lane);
            const int j0 = t * 64;
            if (j0 <= qwb + 31) {  // wave-uniform: skip fully-masked tiles (barriers still hit)
                const short* kt = kbuf[cur];
                const short* vtile = vbuf[cur];
                short8 kf[4][2];
#pragma unroll
                for (int tt = 0; tt < 4; tt++)
#pragma unroll
                    for (int c = 0; c < 2; c++) {
                        int off = (((tt * 16 + l15) * 128) + c * 64 + lhi * 16) ^ swz;
                        kf[tt][c] = *(const short8*)((const char*)kt + off);
                    }
                floatx4 sacc[2][4];
#pragma unroll
                for (int qg = 0; qg < 2; qg++)
#pragma unroll
                    for (int tt = 0; tt < 4; tt++) sacc[qg][tt] = z;
#pragma unroll
                for (int tt = 0; tt < 4; tt++)
#pragma unroll
                    for (int c = 0; c < 2; c++) {
                        sacc[0][tt] = mfma16(kf[tt][c], qf[0][c], sacc[0][tt]);
                        sacc[1][tt] = mfma16(kf[tt][c], qf[1][c], sacc[1][tt]);
                    }
                short4v vf[4][4];
#pragma unroll
                for (int tt = 0; tt < 4; tt++)
#pragma unroll
                    for (int dt = 0; dt < 4; dt++) {
                        int off = (((dt * 16 + l15) * 128) + tt * 32 + lhi * 8) ^ swz;
                        vf[tt][dt] = *(const short4v*)((const char*)vtile + off);
                    }
                float pd[16];
#pragma unroll
                for (int tt = 0; tt < 4; tt++) {
                    float4 pmv = *(const float4*)(pmb + j0 + tt * 16 + lhi * 4);
                    pd[tt * 4 + 0] = (1.f - pmv.x) * -1e9f;
                    pd[tt * 4 + 1] = (1.f - pmv.y) * -1e9f;
                    pd[tt * 4 + 2] = (1.f - pmv.z) * -1e9f;
                    pd[tt * 4 + 3] = (1.f - pmv.w) * -1e9f;
                }
#pragma unroll
                for (int qg = 0; qg < 2; qg++) {
                    const int q = qwb + qg * 16 + l15;
                    const bool domask = (j0 + 63 > qwb + qg * 16);
                    float mx = -1e30f;
#pragma unroll
                    for (int tt = 0; tt < 4; tt++)
#pragma unroll
                        for (int r = 0; r < 4; r++) {
                            float v = sacc[qg][tt][r] + pd[tt * 4 + r];
                            if (domask) {
                                int key = j0 + tt * 16 + lhi * 4 + r;
                                v = (key > q) ? -1e30f : v;
                            }
                            sacc[qg][tt][r] = v;
                            mx = fmaxf(mx, v);
                        }
                    mx = fmaxf(mx, __shfl_xor(mx, 16, 64));
                    mx = fmaxf(mx, __shfl_xor(mx, 32, 64));
                    float mnew = fmaxf(m_r[qg], mx);
                    float sf = __expf(m_r[qg] - mnew);
                    m_r[qg] = mnew;
                    l_part[qg] *= sf;
#pragma unroll
                    for (int r = 0; r < 4; r++) {
                        float sfr = __shfl(sf, lhi * 4 + r, 64);
#pragma unroll
                        for (int dt = 0; dt < 4; dt++) oacc[qg][dt][r] *= sfr;
                    }
#pragma unroll
                    for (int tt = 0; tt < 4; tt++) {
                        float p0 = __expf(sacc[qg][tt][0] - m_r[qg]);
                        float p1 = __expf(sacc[qg][tt][1] - m_r[qg]);
                        float p2 = __expf(sacc[qg][tt][2] - m_r[qg]);
                        float p3 = __expf(sacc[qg][tt][3] - m_r[qg]);
                        l_part[qg] += (p0 + p1) + (p2 + p3);
                        short4v af;
                        af.x = f2bf(p0);
                        af.y = f2bf(p1);
                        af.z = f2bf(p2);
                        af.w = f2bf(p3);
#pragma unroll
                        for (int dt = 0; dt < 4; dt++)
                            oacc[qg][dt] = mfma16k16(af, vf[tt][dt], oacc[qg][dt]);
                    }
                }
            }
            asm volatile("s_waitcnt vmcnt(0)" ::: "memory");
            __syncthreads();
        }

        // ---- epilogue for this phase ----
#pragma unroll
        for (int qg = 0; qg < 2; qg++) {
            float lsum = l_part[qg];
            lsum += __shfl_xor(lsum, 16, 64);
            lsum += __shfl_xor(lsum, 32, 64);
            float rinv[4];
#pragma unroll
            for (int r = 0; r < 4; r++)
                rinv[r] = 1.0f / __shfl(lsum, lhi * 4 + r, 64);
#pragma unroll
            for (int dt = 0; dt < 4; dt++) {
                int d = dt * 16 + l15;
#pragma unroll
                for (int r = 0; r < 4; r++) {
                    int row = qwb + qg * 16 + lhi * 4 + r;
                    float o = oacc[qg][dt][r] * rinv[r];
                    ao[((size_t)(b * S_LEN) + row) * DMODEL + h * DEPTH + d] = f2bf(o);
                }
            }
        }
    }
}

extern "C" void kernel_launch(void* const* d_in, const int* in_sizes, int n_in,
                              void* d_out, int out_size, void* d_ws, size_t ws_size,
                              hipStream_t stream) {
    const float* x    = (const float*)d_in[0];
    const float* pm   = (const float*)d_in[1];
    const float* wq_w = (const float*)d_in[2];
    const float* wq_b = (const float*)d_in[3];
    const float* wk_w = (const float*)d_in[4];
    const float* wk_b = (const float*)d_in[5];
    const float* wv_w = (const float*)d_in[6];
    const float* wv_b = (const float*)d_in[7];
    const float* wo_w = (const float*)d_in[8];
    const float* wo_b = (const float*)d_in[9];
    float* out = (float*)d_out;

    char* ws = (char*)d_ws;
    const size_t MB = 1024 * 1024;
    short* xb  = (short*)(ws);            // 8 MB : x bf16 (4096x1024)
    short* wqb = (short*)(ws + 8 * MB);   // 2 MB : wq^T bf16
    short* wkb = (short*)(ws + 10 * MB);
    short* wvb = (short*)(ws + 12 * MB);
    short* wob = (short*)(ws + 14 * MB);
    short* qh  = (short*)(ws + 16 * MB);  // 8 MB : Q (B,H,S,depth) bf16, pre-scaled by 0.125
    short* kh  = (short*)(ws + 24 * MB);  // 8 MB : K (B,H,S,depth) bf16
    short* vt  = (short*)(ws + 32 * MB);  // 8 MB : V^T (B,H,depth,S) bf16
    short* ao  = (short*)(ws + 40 * MB);  // 8 MB : attn out (B,S,D) bf16

    convert_x_kernel<<<4096, 256, 0, stream>>>(x, xb);
    wt_kernel<<<dim3(32, 32, 4), dim3(32, 8), 0, stream>>>(wq_w, wk_w, wv_w, wo_w,
                                                           wqb, wkb, wvb, wob);
    gemm_qkv<<<dim3(8, 32, 3), 256, 0, stream>>>(xb, wqb, wkb, wvb, wq_b, wk_b, wv_b,
                                                 qh, kh, vt);
    attn_kernel<<<dim3(32, 8), 256, 0, stream>>>(qh, kh, vt, pm, ao);
    gemm_out<<<dim3(8, 32), 256, 0, stream>>>(ao, wob, wo_b, out);
}

// Round 12
// 141.434 us; speedup vs baseline: 1.3363x; 1.0111x over previous
//
#include <hip/hip_runtime.h>
#include <math.h>

#define S_LEN 2048
#define DMODEL 1024
#define NH 16
#define DEPTH 64
#define BATCH 2
#define MTOT (BATCH * S_LEN) // 4096

typedef __attribute__((ext_vector_type(8))) short short8;
typedef __attribute__((ext_vector_type(4))) short short4v;
typedef __attribute__((ext_vector_type(4))) float floatx4;

typedef const __attribute__((address_space(1))) unsigned gas_u32;
typedef __attribute__((address_space(3))) unsigned las_u32;

__device__ __forceinline__ short f2bf(float f) {
    union { float f; unsigned u; } v; v.f = f;
    unsigned r = v.u + 0x7fffu + ((v.u >> 16) & 1u);
    return (short)(r >> 16);
}

__device__ __forceinline__ floatx4 mfma16(short8 a, short8 b, floatx4 c) {
    return __builtin_amdgcn_mfma_f32_16x16x32_bf16(a, b, c, 0, 0, 0);
}

// K=16 bf16 MFMA: A/B are 4 bf16 per lane (2 VGPRs). A: row=lane&15, k=(lane>>4)*4+e.
#if __has_builtin(__builtin_amdgcn_mfma_f32_16x16x16bf16_1k)
__device__ __forceinline__ floatx4 mfma16k16(short4v a, short4v b, floatx4 c) {
    return __builtin_amdgcn_mfma_f32_16x16x16bf16_1k(a, b, c, 0, 0, 0);
}
#else
__device__ __forceinline__ floatx4 mfma16k16(short4v a, short4v b, floatx4 c) {
    asm volatile("v_mfma_f32_16x16x16_bf16 %0, %1, %2, %0\n\ts_nop 7\n\ts_nop 7"
                 : "+v"(c) : "v"(a), "v"(b));
    return c;
}
#endif

// ---------------- convert x: fp32 -> bf16 ----------------
__global__ __launch_bounds__(256) void convert_x_kernel(const float* __restrict__ x,
                                                        short* __restrict__ xb) {
    int i = (blockIdx.x * 256 + threadIdx.x) * 4;
    float4 v = *(const float4*)(x + i);
    short4v o;
    o.x = f2bf(v.x); o.y = f2bf(v.y); o.z = f2bf(v.z); o.w = f2bf(v.w);
    *(short4v*)(xb + i) = o;
}

// ---------------- transpose+convert weights: (K,N) fp32 -> (N,K) bf16 ----------------
__global__ __launch_bounds__(256) void wt_kernel(const float* __restrict__ w0, const float* __restrict__ w1,
                                                 const float* __restrict__ w2, const float* __restrict__ w3,
                                                 short* __restrict__ o0, short* __restrict__ o1,
                                                 short* __restrict__ o2, short* __restrict__ o3) {
    const float* src; short* dst;
    switch (blockIdx.z) {
        case 0: src = w0; dst = o0; break;
        case 1: src = w1; dst = o1; break;
        case 2: src = w2; dst = o2; break;
        default: src = w3; dst = o3; break;
    }
    __shared__ float tile[32][33];
    int tx = threadIdx.x, ty = threadIdx.y;
    int c = blockIdx.x * 32 + tx;
    int r0 = blockIdx.y * 32;
#pragma unroll
    for (int i = 0; i < 4; i++)
        tile[ty + i * 8][tx] = src[(size_t)(r0 + ty + i * 8) * DMODEL + c];
    __syncthreads();
    int co = blockIdx.y * 32 + tx;
    int ro = blockIdx.x * 32;
#pragma unroll
    for (int i = 0; i < 4; i++)
        dst[(size_t)(ro + ty + i * 8) * DMODEL + co] = f2bf(tile[tx][ty + i * 8]);
}

// ---------------- GEMM v2: global_load_lds staged, XOR-swizzled, double-buffered ----------------
__device__ __forceinline__ void stage_tile(const short* __restrict__ src, int row0, int k0,
                                           short* dstLds, int tid) {
#pragma unroll
    for (int s = 0; s < 4; s++) {
        const int p = s * 4096 + tid * 16;           // linear LDS byte position
        const int q = p ^ (((p >> 7) & 7) << 4);     // inverse-swizzled tile byte
        const char* srcp = (const char*)src + (size_t)(row0 + (q >> 7)) * (DMODEL * 2)
                         + k0 * 2 + (q & 127);
        __builtin_amdgcn_global_load_lds((gas_u32*)srcp,
                                         (las_u32*)((char*)dstLds + p), 16, 0, 0);
    }
}

__device__ __forceinline__ void gemm_core(const short* __restrict__ A,
                                          const short* __restrict__ Bt,
                                          int m0, int n0,
                                          short* Ab0, short* Ab1, short* Bb0, short* Bb1,
                                          floatx4 acc[4][4]) {
    const int tid = threadIdx.x;
    const int lane = tid & 63;
    const int w = tid >> 6;
    const int wr = w >> 1, wc = w & 1;
    const int l15 = lane & 15, lhi = lane >> 4;
    const int swz = (l15 & 7) << 4;

    stage_tile(A, m0, 0, Ab0, tid);
    stage_tile(Bt, n0, 0, Bb0, tid);
    asm volatile("s_waitcnt vmcnt(0)" ::: "memory");
    __syncthreads();

    for (int ks = 0; ks < 16; ks++) {
        const char* Ac = (const char*)((ks & 1) ? Ab1 : Ab0);
        const char* Bc = (const char*)((ks & 1) ? Bb1 : Bb0);
        if (ks < 15) {
            stage_tile(A, m0, (ks + 1) * 64, (ks & 1) ? Ab0 : Ab1, tid);
            stage_tile(Bt, n0, (ks + 1) * 64, (ks & 1) ? Bb0 : Bb1, tid);
        }
#pragma unroll
        for (int kkb = 0; kkb < 128; kkb += 64) {   // byte offset of 32-element K-slice
            short8 af[4], bf[4];
#pragma unroll
            for (int i = 0; i < 4; i++) {
                int row = wr * 64 + i * 16 + l15;
                af[i] = *(const short8*)(Ac + ((row * 128 + kkb + lhi * 16) ^ swz));
            }
#pragma unroll
            for (int j = 0; j < 4; j++) {
                int row = wc * 64 + j * 16 + l15;
                bf[j] = *(const short8*)(Bc + ((row * 128 + kkb + lhi * 16) ^ swz));
            }
#pragma unroll
            for (int i = 0; i < 4; i++)
#pragma unroll
                for (int j = 0; j < 4; j++)
                    acc[i][j] = mfma16(af[i], bf[j], acc[i][j]);
        }
        asm volatile("s_waitcnt vmcnt(0)" ::: "memory");
        __syncthreads();
    }
}

// ---------------- QKV GEMM: out layouts per-head; V transposed; Q pre-scaled ----------------
__global__ __launch_bounds__(256) void gemm_qkv(const short* __restrict__ A,
                                                const short* __restrict__ wq, const short* __restrict__ wk,
                                                const short* __restrict__ wv,
                                                const float* __restrict__ bq, const float* __restrict__ bk,
                                                const float* __restrict__ bv,
                                                short* __restrict__ qh, short* __restrict__ kh,
                                                short* __restrict__ vt) {
    __shared__ __align__(16) short Ab[2][8192];
    __shared__ __align__(16) short Bb[2][8192];
    const int mode = blockIdx.z;
    const short* Bt = (mode == 0) ? wq : (mode == 1) ? wk : wv;
    const float* bias = (mode == 0) ? bq : (mode == 1) ? bk : bv;

    floatx4 acc[4][4];
    floatx4 z = {0.f, 0.f, 0.f, 0.f};
#pragma unroll
    for (int i = 0; i < 4; i++)
#pragma unroll
        for (int j = 0; j < 4; j++) acc[i][j] = z;

    const int m0 = blockIdx.y * 128, n0 = blockIdx.x * 128;
    gemm_core(A, Bt, m0, n0, Ab[0], Ab[1], Bb[0], Bb[1], acc);

    const int lane = threadIdx.x & 63;
    const int w = threadIdx.x >> 6;
    const int wr = w >> 1, wc = w & 1;
    const int l15 = lane & 15, lhi = lane >> 4;
    const float qscale = (mode == 0) ? 0.125f : 1.0f;  // fold 1/sqrt(depth) into Q
#pragma unroll
    for (int i = 0; i < 4; i++) {
#pragma unroll
        for (int j = 0; j < 4; j++) {
            int n = n0 + wc * 64 + j * 16 + l15;
            float bv_ = bias[n];
            int h = n >> 6, d = n & 63;
            int mbase = m0 + wr * 64 + i * 16 + (lhi << 2);
#pragma unroll
            for (int r = 0; r < 4; r++) {
                int m = mbase + r;
                int b = m >> 11, s = m & 2047;
                short val = f2bf((acc[i][j][r] + bv_) * qscale);
                if (mode == 0)
                    qh[((size_t)(b * NH + h) * S_LEN + s) * DEPTH + d] = val;
                else if (mode == 1)
                    kh[((size_t)(b * NH + h) * S_LEN + s) * DEPTH + d] = val;
                else
                    vt[((size_t)(b * NH + h) * DEPTH + d) * S_LEN + s] = val;
            }
        }
    }
}

// ---------------- output projection GEMM: fp32 out ----------------
__global__ __launch_bounds__(256) void gemm_out(const short* __restrict__ A,
                                                const short* __restrict__ Bt,
                                                const float* __restrict__ bias,
                                                float* __restrict__ out) {
    __shared__ __align__(16) short Ab[2][8192];
    __shared__ __align__(16) short Bb[2][8192];
    floatx4 acc[4][4];
    floatx4 z = {0.f, 0.f, 0.f, 0.f};
#pragma unroll
    for (int i = 0; i < 4; i++)
#pragma unroll
        for (int j = 0; j < 4; j++) acc[i][j] = z;

    const int m0 = blockIdx.y * 128, n0 = blockIdx.x * 128;
    gemm_core(A, Bt, m0, n0, Ab[0], Ab[1], Bb[0], Bb[1], acc);

    const int lane = threadIdx.x & 63;
    const int w = threadIdx.x >> 6;
    const int wr = w >> 1, wc = w & 1;
    const int l15 = lane & 15, lhi = lane >> 4;
#pragma unroll
    for (int i = 0; i < 4; i++) {
#pragma unroll
        for (int j = 0; j < 4; j++) {
            int n = n0 + wc * 64 + j * 16 + l15;
            float bv_ = bias[n];
            int mbase = m0 + wr * 64 + i * 16 + (lhi << 2);
#pragma unroll
            for (int r = 0; r < 4; r++) {
                int m = mbase + r;
                out[(size_t)m * DMODEL + n] = acc[i][j][r] + bv_;
            }
        }
    }
}

// ---------------- flash attention v10: 512 blocks, 2/CU, XCD-local, heavy-first ----------------
// Grid (bh=32, y=16): linear id = bh + 32*y -> XCD = bh%8 (4 heads/XCD -> 2MB K/V
// L2-resident, round-11-proven). chunk = 15-y so heavy blocks dispatch first (LPT
// packing of the causal triangle). 2 blocks/CU -> 2 waves/SIMD for latency hiding
// (round-11 was 1 wave/SIMD, 60% idle). Inner math identical to round-7/10/11.

__device__ __forceinline__ void stage_kv(const short* __restrict__ kb_j0,  // kb + j0*DEPTH
                                         const short* __restrict__ vb, int j0,
                                         short* kt, short* vt_, int wid, int lane) {
#pragma unroll
    for (int s = 0; s < 2; s++) {
        const int seg = (s * 4 + wid) * 1024;        // byte segment of the 8KB tile
        const int p = seg + lane * 16;               // linear LDS byte position
        const int q = p ^ (((p >> 7) & 7) << 4);     // inverse-swizzled source offset
        __builtin_amdgcn_global_load_lds((gas_u32*)((const char*)kb_j0 + q),
                                         (las_u32*)((char*)kt + seg), 16, 0, 0);
        const char* vsrc = (const char*)vb + (size_t)(q >> 7) * (S_LEN * 2) + j0 * 2 + (q & 127);
        __builtin_amdgcn_global_load_lds((gas_u32*)vsrc,
                                         (las_u32*)((char*)vt_ + seg), 16, 0, 0);
    }
}

__global__ __launch_bounds__(256, 2) void attn_kernel(const short* __restrict__ qh,
                                                      const short* __restrict__ kh,
                                                      const short* __restrict__ vt,
                                                      const float* __restrict__ pm,
                                                      short* __restrict__ ao) {
    __shared__ short kbuf[2][4096];
    __shared__ short vbuf[2][4096];
    const int lane = threadIdx.x & 63;
    const int wid = threadIdx.x >> 6;  // 0..3
    const int bh = blockIdx.x;         // bh fastest -> same-head blocks share an XCD
    const int chunk = 15 - (int)blockIdx.y;  // heavy-first dispatch
    const int b = bh >> 4, h = bh & 15;
    const short* qbp = qh + (size_t)bh * S_LEN * DEPTH;
    const short* kb = kh + (size_t)bh * S_LEN * DEPTH;
    const short* vb = vt + (size_t)bh * DEPTH * S_LEN;
    const float* pmb = pm + b * S_LEN;
    const int l15 = lane & 15, lhi = lane >> 4;
    const int swz = (l15 & 7) << 4;

    const int qwb = chunk * 128 + wid * 32;

    short8 qf[2][2];
#pragma unroll
    for (int qg = 0; qg < 2; qg++)
#pragma unroll
        for (int c = 0; c < 2; c++)
            qf[qg][c] = *(const short8*)(qbp + (size_t)(qwb + qg * 16 + l15) * DEPTH + c * 32 + lhi * 8);

    float m_r[2] = {-1e30f, -1e30f};
    float l_part[2] = {0.f, 0.f};
    floatx4 oacc[2][4];
    floatx4 z = {0.f, 0.f, 0.f, 0.f};
#pragma unroll
    for (int qg = 0; qg < 2; qg++)
#pragma unroll
        for (int dt = 0; dt < 4; dt++) oacc[qg][dt] = z;

    const int NT = 2 * chunk + 2;  // key tiles 0 .. chunk*128+64
    stage_kv(kb, vb, 0, kbuf[0], vbuf[0], wid, lane);
    __syncthreads();

    for (int t = 0; t < NT; t++) {
        const int cur = t & 1;
        if (t + 1 < NT)
            stage_kv(kb + (size_t)(t + 1) * 64 * DEPTH, vb, (t + 1) * 64,
                     kbuf[cur ^ 1], vbuf[cur ^ 1], wid, lane);
        const int j0 = t * 64;
        if (j0 <= qwb + 31) {  // wave-uniform: skip fully-masked tiles (barriers still hit)
            const short* kt = kbuf[cur];
            const short* vtile = vbuf[cur];
            short8 kf[4][2];
#pragma unroll
            for (int tt = 0; tt < 4; tt++)
#pragma unroll
                for (int c = 0; c < 2; c++) {
                    int off = (((tt * 16 + l15) * 128) + c * 64 + lhi * 16) ^ swz;
                    kf[tt][c] = *(const short8*)((const char*)kt + off);
                }
            floatx4 sacc[2][4];
#pragma unroll
            for (int qg = 0; qg < 2; qg++)
#pragma unroll
                for (int tt = 0; tt < 4; tt++) sacc[qg][tt] = z;
#pragma unroll
            for (int tt = 0; tt < 4; tt++)
#pragma unroll
                for (int c = 0; c < 2; c++) {
                    sacc[0][tt] = mfma16(kf[tt][c], qf[0][c], sacc[0][tt]);
                    sacc[1][tt] = mfma16(kf[tt][c], qf[1][c], sacc[1][tt]);
                }
            short4v vf[4][4];
#pragma unroll
            for (int tt = 0; tt < 4; tt++)
#pragma unroll
                for (int dt = 0; dt < 4; dt++) {
                    int off = (((dt * 16 + l15) * 128) + tt * 32 + lhi * 8) ^ swz;
                    vf[tt][dt] = *(const short4v*)((const char*)vtile + off);
                }
            float pd[16];
#pragma unroll
            for (int tt = 0; tt < 4; tt++) {
                float4 pmv = *(const float4*)(pmb + j0 + tt * 16 + lhi * 4);
                pd[tt * 4 + 0] = (1.f - pmv.x) * -1e9f;
                pd[tt * 4 + 1] = (1.f - pmv.y) * -1e9f;
                pd[tt * 4 + 2] = (1.f - pmv.z) * -1e9f;
                pd[tt * 4 + 3] = (1.f - pmv.w) * -1e9f;
            }
#pragma unroll
            for (int qg = 0; qg < 2; qg++) {
                const int q = qwb + qg * 16 + l15;
                const bool domask = (j0 + 63 > qwb + qg * 16);
                float mx = -1e30f;
#pragma unroll
                for (int tt = 0; tt < 4; tt++)
#pragma unroll
                    for (int r = 0; r < 4; r++) {
                        float v = sacc[qg][tt][r] + pd[tt * 4 + r];
                        if (domask) {
                            int key = j0 + tt * 16 + lhi * 4 + r;
                            v = (key > q) ? -1e30f : v;
                        }
                        sacc[qg][tt][r] = v;
                        mx = fmaxf(mx, v);
                    }
                mx = fmaxf(mx, __shfl_xor(mx, 16, 64));
                mx = fmaxf(mx, __shfl_xor(mx, 32, 64));
                float mnew = fmaxf(m_r[qg], mx);
                float sf = __expf(m_r[qg] - mnew);
                m_r[qg] = mnew;
                l_part[qg] *= sf;
#pragma unroll
                for (int r = 0; r < 4; r++) {
                    float sfr = __shfl(sf, lhi * 4 + r, 64);
#pragma unroll
                    for (int dt = 0; dt < 4; dt++) oacc[qg][dt][r] *= sfr;
                }
#pragma unroll
                for (int tt = 0; tt < 4; tt++) {
                    float p0 = __expf(sacc[qg][tt][0] - m_r[qg]);
                    float p1 = __expf(sacc[qg][tt][1] - m_r[qg]);
                    float p2 = __expf(sacc[qg][tt][2] - m_r[qg]);
                    float p3 = __expf(sacc[qg][tt][3] - m_r[qg]);
                    l_part[qg] += (p0 + p1) + (p2 + p3);
                    short4v af;
                    af.x = f2bf(p0);
                    af.y = f2bf(p1);
                    af.z = f2bf(p2);
                    af.w = f2bf(p3);
#pragma unroll
                    for (int dt = 0; dt < 4; dt++)
                        oacc[qg][dt] = mfma16k16(af, vf[tt][dt], oacc[qg][dt]);
                }
            }
        }
        asm volatile("s_waitcnt vmcnt(0)" ::: "memory");
        __syncthreads();
    }

    // ---- epilogue: reduce per-lane partial sums once ----
#pragma unroll
    for (int qg = 0; qg < 2; qg++) {
        float lsum = l_part[qg];
        lsum += __shfl_xor(lsum, 16, 64);
        lsum += __shfl_xor(lsum, 32, 64);
        float rinv[4];
#pragma unroll
        for (int r = 0; r < 4; r++)
            rinv[r] = 1.0f / __shfl(lsum, lhi * 4 + r, 64);
#pragma unroll
        for (int dt = 0; dt < 4; dt++) {
            int d = dt * 16 + l15;
#pragma unroll
            for (int r = 0; r < 4; r++) {
                int row = qwb + qg * 16 + lhi * 4 + r;
                float o = oacc[qg][dt][r] * rinv[r];
                ao[((size_t)(b * S_LEN) + row) * DMODEL + h * DEPTH + d] = f2bf(o);
            }
        }
    }
}

extern "C" void kernel_launch(void* const* d_in, const int* in_sizes, int n_in,
                              void* d_out, int out_size, void* d_ws, size_t ws_size,
                              hipStream_t stream) {
    const float* x    = (const float*)d_in[0];
    const float* pm   = (const float*)d_in[1];
    const float* wq_w = (const float*)d_in[2];
    const float* wq_b = (const float*)d_in[3];
    const float* wk_w = (const float*)d_in[4];
    const float* wk_b = (const float*)d_in[5];
    const float* wv_w = (const float*)d_in[6];
    const float* wv_b = (const float*)d_in[7];
    const float* wo_w = (const float*)d_in[8];
    const float* wo_b = (const float*)d_in[9];
    float* out = (float*)d_out;

    char* ws = (char*)d_ws;
    const size_t MB = 1024 * 1024;
    short* xb  = (short*)(ws);            // 8 MB : x bf16 (4096x1024)
    short* wqb = (short*)(ws + 8 * MB);   // 2 MB : wq^T bf16
    short* wkb = (short*)(ws + 10 * MB);
    short* wvb = (short*)(ws + 12 * MB);
    short* wob = (short*)(ws + 14 * MB);
    short* qh  = (short*)(ws + 16 * MB);  // 8 MB : Q (B,H,S,depth) bf16, pre-scaled by 0.125
    short* kh  = (short*)(ws + 24 * MB);  // 8 MB : K (B,H,S,depth) bf16
    short* vt  = (short*)(ws + 32 * MB);  // 8 MB : V^T (B,H,depth,S) bf16
    short* ao  = (short*)(ws + 40 * MB);  // 8 MB : attn out (B,S,D) bf16

    convert_x_kernel<<<4096, 256, 0, stream>>>(x, xb);
    wt_kernel<<<dim3(32, 32, 4), dim3(32, 8), 0, stream>>>(wq_w, wk_w, wv_w, wo_w,
                                                           wqb, wkb, wvb, wob);
    gemm_qkv<<<dim3(8, 32, 3), 256, 0, stream>>>(xb, wqb, wkb, wvb, wq_b, wk_b, wv_b,
                                                 qh, kh, vt);
    attn_kernel<<<dim3(32, 16), 256, 0, stream>>>(qh, kh, vt, pm, ao);
    gemm_out<<<dim3(8, 32), 256, 0, stream>>>(ao, wob, wo_b, out);
}

// Round 13
// 140.994 us; speedup vs baseline: 1.3405x; 1.0031x over previous
//
#include <hip/hip_runtime.h>
#include <math.h>

#define S_LEN 2048
#define DMODEL 1024
#define NH 16
#define DEPTH 64
#define BATCH 2
#define MTOT (BATCH * S_LEN) // 4096

typedef __attribute__((ext_vector_type(8))) short short8;
typedef __attribute__((ext_vector_type(4))) short short4v;
typedef __attribute__((ext_vector_type(4))) float floatx4;

typedef const __attribute__((address_space(1))) unsigned gas_u32;
typedef __attribute__((address_space(3))) unsigned las_u32;

__device__ __forceinline__ short f2bf(float f) {
    union { float f; unsigned u; } v; v.f = f;
    unsigned r = v.u + 0x7fffu + ((v.u >> 16) & 1u);
    return (short)(r >> 16);
}

// Pack two fp32 -> two bf16 in one dword, round-half-up (+0x8000, truncate),
// paired via one v_perm_b32. Valid for finite non-NaN inputs (P in [0,1]).
// perm pool: bytes 0-3 = S1, 4-7 = S0; sel 0x07060302 -> [a.b2 a.b3 b.b2 b.b3].
__device__ __forceinline__ unsigned packbf2(float lo, float hi) {
    union { float f; unsigned u; } a, b;
    a.f = lo; b.f = hi;
    return __builtin_amdgcn_perm(b.u + 0x8000u, a.u + 0x8000u, 0x07060302u);
}

__device__ __forceinline__ floatx4 mfma16(short8 a, short8 b, floatx4 c) {
    return __builtin_amdgcn_mfma_f32_16x16x32_bf16(a, b, c, 0, 0, 0);
}

// K=16 bf16 MFMA: A/B are 4 bf16 per lane (2 VGPRs). A: row=lane&15, k=(lane>>4)*4+e.
#if __has_builtin(__builtin_amdgcn_mfma_f32_16x16x16bf16_1k)
__device__ __forceinline__ floatx4 mfma16k16(short4v a, short4v b, floatx4 c) {
    return __builtin_amdgcn_mfma_f32_16x16x16bf16_1k(a, b, c, 0, 0, 0);
}
#else
__device__ __forceinline__ floatx4 mfma16k16(short4v a, short4v b, floatx4 c) {
    asm volatile("v_mfma_f32_16x16x16_bf16 %0, %1, %2, %0\n\ts_nop 7\n\ts_nop 7"
                 : "+v"(c) : "v"(a), "v"(b));
    return c;
}
#endif

// ---------------- convert x: fp32 -> bf16 ----------------
__global__ __launch_bounds__(256) void convert_x_kernel(const float* __restrict__ x,
                                                        short* __restrict__ xb) {
    int i = (blockIdx.x * 256 + threadIdx.x) * 4;
    float4 v = *(const float4*)(x + i);
    short4v o;
    o.x = f2bf(v.x); o.y = f2bf(v.y); o.z = f2bf(v.z); o.w = f2bf(v.w);
    *(short4v*)(xb + i) = o;
}

// ---------------- transpose+convert weights: (K,N) fp32 -> (N,K) bf16 ----------------
__global__ __launch_bounds__(256) void wt_kernel(const float* __restrict__ w0, const float* __restrict__ w1,
                                                 const float* __restrict__ w2, const float* __restrict__ w3,
                                                 short* __restrict__ o0, short* __restrict__ o1,
                                                 short* __restrict__ o2, short* __restrict__ o3) {
    const float* src; short* dst;
    switch (blockIdx.z) {
        case 0: src = w0; dst = o0; break;
        case 1: src = w1; dst = o1; break;
        case 2: src = w2; dst = o2; break;
        default: src = w3; dst = o3; break;
    }
    __shared__ float tile[32][33];
    int tx = threadIdx.x, ty = threadIdx.y;
    int c = blockIdx.x * 32 + tx;
    int r0 = blockIdx.y * 32;
#pragma unroll
    for (int i = 0; i < 4; i++)
        tile[ty + i * 8][tx] = src[(size_t)(r0 + ty + i * 8) * DMODEL + c];
    __syncthreads();
    int co = blockIdx.y * 32 + tx;
    int ro = blockIdx.x * 32;
#pragma unroll
    for (int i = 0; i < 4; i++)
        dst[(size_t)(ro + ty + i * 8) * DMODEL + co] = f2bf(tile[tx][ty + i * 8]);
}

// ---------------- GEMM v2: global_load_lds staged, XOR-swizzled, double-buffered ----------------
__device__ __forceinline__ void stage_tile(const short* __restrict__ src, int row0, int k0,
                                           short* dstLds, int tid) {
#pragma unroll
    for (int s = 0; s < 4; s++) {
        const int p = s * 4096 + tid * 16;           // linear LDS byte position
        const int q = p ^ (((p >> 7) & 7) << 4);     // inverse-swizzled tile byte
        const char* srcp = (const char*)src + (size_t)(row0 + (q >> 7)) * (DMODEL * 2)
                         + k0 * 2 + (q & 127);
        __builtin_amdgcn_global_load_lds((gas_u32*)srcp,
                                         (las_u32*)((char*)dstLds + p), 16, 0, 0);
    }
}

__device__ __forceinline__ void gemm_core(const short* __restrict__ A,
                                          const short* __restrict__ Bt,
                                          int m0, int n0,
                                          short* Ab0, short* Ab1, short* Bb0, short* Bb1,
                                          floatx4 acc[4][4]) {
    const int tid = threadIdx.x;
    const int lane = tid & 63;
    const int w = tid >> 6;
    const int wr = w >> 1, wc = w & 1;
    const int l15 = lane & 15, lhi = lane >> 4;
    const int swz = (l15 & 7) << 4;

    stage_tile(A, m0, 0, Ab0, tid);
    stage_tile(Bt, n0, 0, Bb0, tid);
    asm volatile("s_waitcnt vmcnt(0)" ::: "memory");
    __syncthreads();

    for (int ks = 0; ks < 16; ks++) {
        const char* Ac = (const char*)((ks & 1) ? Ab1 : Ab0);
        const char* Bc = (const char*)((ks & 1) ? Bb1 : Bb0);
        if (ks < 15) {
            stage_tile(A, m0, (ks + 1) * 64, (ks & 1) ? Ab0 : Ab1, tid);
            stage_tile(Bt, n0, (ks + 1) * 64, (ks & 1) ? Bb0 : Bb1, tid);
        }
#pragma unroll
        for (int kkb = 0; kkb < 128; kkb += 64) {   // byte offset of 32-element K-slice
            short8 af[4], bf[4];
#pragma unroll
            for (int i = 0; i < 4; i++) {
                int row = wr * 64 + i * 16 + l15;
                af[i] = *(const short8*)(Ac + ((row * 128 + kkb + lhi * 16) ^ swz));
            }
#pragma unroll
            for (int j = 0; j < 4; j++) {
                int row = wc * 64 + j * 16 + l15;
                bf[j] = *(const short8*)(Bc + ((row * 128 + kkb + lhi * 16) ^ swz));
            }
#pragma unroll
            for (int i = 0; i < 4; i++)
#pragma unroll
                for (int j = 0; j < 4; j++)
                    acc[i][j] = mfma16(af[i], bf[j], acc[i][j]);
        }
        asm volatile("s_waitcnt vmcnt(0)" ::: "memory");
        __syncthreads();
    }
}

// ---------------- QKV GEMM: out layouts per-head; V transposed; Q pre-scaled ----------------
__global__ __launch_bounds__(256) void gemm_qkv(const short* __restrict__ A,
                                                const short* __restrict__ wq, const short* __restrict__ wk,
                                                const short* __restrict__ wv,
                                                const float* __restrict__ bq, const float* __restrict__ bk,
                                                const float* __restrict__ bv,
                                                short* __restrict__ qh, short* __restrict__ kh,
                                                short* __restrict__ vt) {
    __shared__ __align__(16) short Ab[2][8192];
    __shared__ __align__(16) short Bb[2][8192];
    const int mode = blockIdx.z;
    const short* Bt = (mode == 0) ? wq : (mode == 1) ? wk : wv;
    const float* bias = (mode == 0) ? bq : (mode == 1) ? bk : bv;

    floatx4 acc[4][4];
    floatx4 z = {0.f, 0.f, 0.f, 0.f};
#pragma unroll
    for (int i = 0; i < 4; i++)
#pragma unroll
        for (int j = 0; j < 4; j++) acc[i][j] = z;

    const int m0 = blockIdx.y * 128, n0 = blockIdx.x * 128;
    gemm_core(A, Bt, m0, n0, Ab[0], Ab[1], Bb[0], Bb[1], acc);

    const int lane = threadIdx.x & 63;
    const int w = threadIdx.x >> 6;
    const int wr = w >> 1, wc = w & 1;
    const int l15 = lane & 15, lhi = lane >> 4;
    const float qscale = (mode == 0) ? 0.125f : 1.0f;  // fold 1/sqrt(depth) into Q
#pragma unroll
    for (int i = 0; i < 4; i++) {
#pragma unroll
        for (int j = 0; j < 4; j++) {
            int n = n0 + wc * 64 + j * 16 + l15;
            float bv_ = bias[n];
            int h = n >> 6, d = n & 63;
            int mbase = m0 + wr * 64 + i * 16 + (lhi << 2);
#pragma unroll
            for (int r = 0; r < 4; r++) {
                int m = mbase + r;
                int b = m >> 11, s = m & 2047;
                short val = f2bf((acc[i][j][r] + bv_) * qscale);
                if (mode == 0)
                    qh[((size_t)(b * NH + h) * S_LEN + s) * DEPTH + d] = val;
                else if (mode == 1)
                    kh[((size_t)(b * NH + h) * S_LEN + s) * DEPTH + d] = val;
                else
                    vt[((size_t)(b * NH + h) * DEPTH + d) * S_LEN + s] = val;
            }
        }
    }
}

// ---------------- output projection GEMM: fp32 out ----------------
__global__ __launch_bounds__(256) void gemm_out(const short* __restrict__ A,
                                                const short* __restrict__ Bt,
                                                const float* __restrict__ bias,
                                                float* __restrict__ out) {
    __shared__ __align__(16) short Ab[2][8192];
    __shared__ __align__(16) short Bb[2][8192];
    floatx4 acc[4][4];
    floatx4 z = {0.f, 0.f, 0.f, 0.f};
#pragma unroll
    for (int i = 0; i < 4; i++)
#pragma unroll
        for (int j = 0; j < 4; j++) acc[i][j] = z;

    const int m0 = blockIdx.y * 128, n0 = blockIdx.x * 128;
    gemm_core(A, Bt, m0, n0, Ab[0], Ab[1], Bb[0], Bb[1], acc);

    const int lane = threadIdx.x & 63;
    const int w = threadIdx.x >> 6;
    const int wr = w >> 1, wc = w & 1;
    const int l15 = lane & 15, lhi = lane >> 4;
#pragma unroll
    for (int i = 0; i < 4; i++) {
#pragma unroll
        for (int j = 0; j < 4; j++) {
            int n = n0 + wc * 64 + j * 16 + l15;
            float bv_ = bias[n];
            int mbase = m0 + wr * 64 + i * 16 + (lhi << 2);
#pragma unroll
            for (int r = 0; r < 4; r++) {
                int m = mbase + r;
                out[(size_t)m * DMODEL + n] = acc[i][j][r] + bv_;
            }
        }
    }
}

// ---------------- flash attention v11: v10 + perm-packed P (VALU cut) ----------------
// Identical structure to round-12 (512 blocks, 2/CU, XCD-local, heavy-first).
// Single change: P fp32->bf16 pack uses round-half-up + v_perm_b32 pairing
// (6 VALU instrs per 4 values vs ~20 for scalar RNE f2bf) — VALU was the
// busiest pipe (36% vs MFMA 13%).

__device__ __forceinline__ void stage_kv(const short* __restrict__ kb_j0,  // kb + j0*DEPTH
                                         const short* __restrict__ vb, int j0,
                                         short* kt, short* vt_, int wid, int lane) {
#pragma unroll
    for (int s = 0; s < 2; s++) {
        const int seg = (s * 4 + wid) * 1024;        // byte segment of the 8KB tile
        const int p = seg + lane * 16;               // linear LDS byte position
        const int q = p ^ (((p >> 7) & 7) << 4);     // inverse-swizzled source offset
        __builtin_amdgcn_global_load_lds((gas_u32*)((const char*)kb_j0 + q),
                                         (las_u32*)((char*)kt + seg), 16, 0, 0);
        const char* vsrc = (const char*)vb + (size_t)(q >> 7) * (S_LEN * 2) + j0 * 2 + (q & 127);
        __builtin_amdgcn_global_load_lds((gas_u32*)vsrc,
                                         (las_u32*)((char*)vt_ + seg), 16, 0, 0);
    }
}

__global__ __launch_bounds__(256, 2) void attn_kernel(const short* __restrict__ qh,
                                                      const short* __restrict__ kh,
                                                      const short* __restrict__ vt,
                                                      const float* __restrict__ pm,
                                                      short* __restrict__ ao) {
    __shared__ short kbuf[2][4096];
    __shared__ short vbuf[2][4096];
    const int lane = threadIdx.x & 63;
    const int wid = threadIdx.x >> 6;  // 0..3
    const int bh = blockIdx.x;         // bh fastest -> same-head blocks share an XCD
    const int chunk = 15 - (int)blockIdx.y;  // heavy-first dispatch
    const int b = bh >> 4, h = bh & 15;
    const short* qbp = qh + (size_t)bh * S_LEN * DEPTH;
    const short* kb = kh + (size_t)bh * S_LEN * DEPTH;
    const short* vb = vt + (size_t)bh * DEPTH * S_LEN;
    const float* pmb = pm + b * S_LEN;
    const int l15 = lane & 15, lhi = lane >> 4;
    const int swz = (l15 & 7) << 4;

    const int qwb = chunk * 128 + wid * 32;

    short8 qf[2][2];
#pragma unroll
    for (int qg = 0; qg < 2; qg++)
#pragma unroll
        for (int c = 0; c < 2; c++)
            qf[qg][c] = *(const short8*)(qbp + (size_t)(qwb + qg * 16 + l15) * DEPTH + c * 32 + lhi * 8);

    float m_r[2] = {-1e30f, -1e30f};
    float l_part[2] = {0.f, 0.f};
    floatx4 oacc[2][4];
    floatx4 z = {0.f, 0.f, 0.f, 0.f};
#pragma unroll
    for (int qg = 0; qg < 2; qg++)
#pragma unroll
        for (int dt = 0; dt < 4; dt++) oacc[qg][dt] = z;

    const int NT = 2 * chunk + 2;  // key tiles 0 .. chunk*128+64
    stage_kv(kb, vb, 0, kbuf[0], vbuf[0], wid, lane);
    __syncthreads();

    for (int t = 0; t < NT; t++) {
        const int cur = t & 1;
        if (t + 1 < NT)
            stage_kv(kb + (size_t)(t + 1) * 64 * DEPTH, vb, (t + 1) * 64,
                     kbuf[cur ^ 1], vbuf[cur ^ 1], wid, lane);
        const int j0 = t * 64;
        if (j0 <= qwb + 31) {  // wave-uniform: skip fully-masked tiles (barriers still hit)
            const short* kt = kbuf[cur];
            const short* vtile = vbuf[cur];
            short8 kf[4][2];
#pragma unroll
            for (int tt = 0; tt < 4; tt++)
#pragma unroll
                for (int c = 0; c < 2; c++) {
                    int off = (((tt * 16 + l15) * 128) + c * 64 + lhi * 16) ^ swz;
                    kf[tt][c] = *(const short8*)((const char*)kt + off);
                }
            floatx4 sacc[2][4];
#pragma unroll
            for (int qg = 0; qg < 2; qg++)
#pragma unroll
                for (int tt = 0; tt < 4; tt++) sacc[qg][tt] = z;
#pragma unroll
            for (int tt = 0; tt < 4; tt++)
#pragma unroll
                for (int c = 0; c < 2; c++) {
                    sacc[0][tt] = mfma16(kf[tt][c], qf[0][c], sacc[0][tt]);
                    sacc[1][tt] = mfma16(kf[tt][c], qf[1][c], sacc[1][tt]);
                }
            short4v vf[4][4];
#pragma unroll
            for (int tt = 0; tt < 4; tt++)
#pragma unroll
                for (int dt = 0; dt < 4; dt++) {
                    int off = (((dt * 16 + l15) * 128) + tt * 32 + lhi * 8) ^ swz;
                    vf[tt][dt] = *(const short4v*)((const char*)vtile + off);
                }
            float pd[16];
#pragma unroll
            for (int tt = 0; tt < 4; tt++) {
                float4 pmv = *(const float4*)(pmb + j0 + tt * 16 + lhi * 4);
                pd[tt * 4 + 0] = (1.f - pmv.x) * -1e9f;
                pd[tt * 4 + 1] = (1.f - pmv.y) * -1e9f;
                pd[tt * 4 + 2] = (1.f - pmv.z) * -1e9f;
                pd[tt * 4 + 3] = (1.f - pmv.w) * -1e9f;
            }
#pragma unroll
            for (int qg = 0; qg < 2; qg++) {
                const int q = qwb + qg * 16 + l15;
                const bool domask = (j0 + 63 > qwb + qg * 16);
                float mx = -1e30f;
#pragma unroll
                for (int tt = 0; tt < 4; tt++)
#pragma unroll
                    for (int r = 0; r < 4; r++) {
                        float v = sacc[qg][tt][r] + pd[tt * 4 + r];
                        if (domask) {
                            int key = j0 + tt * 16 + lhi * 4 + r;
                            v = (key > q) ? -1e30f : v;
                        }
                        sacc[qg][tt][r] = v;
                        mx = fmaxf(mx, v);
                    }
                mx = fmaxf(mx, __shfl_xor(mx, 16, 64));
                mx = fmaxf(mx, __shfl_xor(mx, 32, 64));
                float mnew = fmaxf(m_r[qg], mx);
                float sf = __expf(m_r[qg] - mnew);
                m_r[qg] = mnew;
                l_part[qg] *= sf;
#pragma unroll
                for (int r = 0; r < 4; r++) {
                    float sfr = __shfl(sf, lhi * 4 + r, 64);
#pragma unroll
                    for (int dt = 0; dt < 4; dt++) oacc[qg][dt][r] *= sfr;
                }
#pragma unroll
                for (int tt = 0; tt < 4; tt++) {
                    float p0 = __expf(sacc[qg][tt][0] - m_r[qg]);
                    float p1 = __expf(sacc[qg][tt][1] - m_r[qg]);
                    float p2 = __expf(sacc[qg][tt][2] - m_r[qg]);
                    float p3 = __expf(sacc[qg][tt][3] - m_r[qg]);
                    l_part[qg] += (p0 + p1) + (p2 + p3);
                    union { unsigned u[2]; short4v s; } cv;
                    cv.u[0] = packbf2(p0, p1);
                    cv.u[1] = packbf2(p2, p3);
#pragma unroll
                    for (int dt = 0; dt < 4; dt++)
                        oacc[qg][dt] = mfma16k16(cv.s, vf[tt][dt], oacc[qg][dt]);
                }
            }
        }
        asm volatile("s_waitcnt vmcnt(0)" ::: "memory");
        __syncthreads();
    }

    // ---- epilogue: reduce per-lane partial sums once ----
#pragma unroll
    for (int qg = 0; qg < 2; qg++) {
        float lsum = l_part[qg];
        lsum += __shfl_xor(lsum, 16, 64);
        lsum += __shfl_xor(lsum, 32, 64);
        float rinv[4];
#pragma unroll
        for (int r = 0; r < 4; r++)
            rinv[r] = 1.0f / __shfl(lsum, lhi * 4 + r, 64);
#pragma unroll
        for (int dt = 0; dt < 4; dt++) {
            int d = dt * 16 + l15;
#pragma unroll
            for (int r = 0; r < 4; r++) {
                int row = qwb + qg * 16 + lhi * 4 + r;
                float o = oacc[qg][dt][r] * rinv[r];
                ao[((size_t)(b * S_LEN) + row) * DMODEL + h * DEPTH + d] = f2bf(o);
            }
        }
    }
}

extern "C" void kernel_launch(void* const* d_in, const int* in_sizes, int n_in,
                              void* d_out, int out_size, void* d_ws, size_t ws_size,
                              hipStream_t stream) {
    const float* x    = (const float*)d_in[0];
    const float* pm   = (const float*)d_in[1];
    const float* wq_w = (const float*)d_in[2];
    const float* wq_b = (const float*)d_in[3];
    const float* wk_w = (const float*)d_in[4];
    const float* wk_b = (const float*)d_in[5];
    const float* wv_w = (const float*)d_in[6];
    const float* wv_b = (const float*)d_in[7];
    const float* wo_w = (const float*)d_in[8];
    const float* wo_b = (const float*)d_in[9];
    float* out = (float*)d_out;

    char* ws = (char*)d_ws;
    const size_t MB = 1024 * 1024;
    short* xb  = (short*)(ws);            // 8 MB : x bf16 (4096x1024)
    short* wqb = (short*)(ws + 8 * MB);   // 2 MB : wq^T bf16
    short* wkb = (short*)(ws + 10 * MB);
    short* wvb = (short*)(ws + 12 * MB);
    short* wob = (short*)(ws + 14 * MB);
    short* qh  = (short*)(ws + 16 * MB);  // 8 MB : Q (B,H,S,depth) bf16, pre-scaled by 0.125
    short* kh  = (short*)(ws + 24 * MB);  // 8 MB : K (B,H,S,depth) bf16
    short* vt  = (short*)(ws + 32 * MB);  // 8 MB : V^T (B,H,depth,S) bf16
    short* ao  = (short*)(ws + 40 * MB);  // 8 MB : attn out (B,S,D) bf16

    convert_x_kernel<<<4096, 256, 0, stream>>>(x, xb);
    wt_kernel<<<dim3(32, 32, 4), dim3(32, 8), 0, stream>>>(wq_w, wk_w, wv_w, wo_w,
                                                           wqb, wkb, wvb, wob);
    gemm_qkv<<<dim3(8, 32, 3), 256, 0, stream>>>(xb, wqb, wkb, wvb, wq_b, wk_b, wv_b,
                                                 qh, kh, vt);
    attn_kernel<<<dim3(32, 16), 256, 0, stream>>>(qh, kh, vt, pm, ao);
    gemm_out<<<dim3(8, 32), 256, 0, stream>>>(ao, wob, wo_b, out);
}

// Round 14
// 140.513 us; speedup vs baseline: 1.3451x; 1.0034x over previous
//
#include <hip/hip_runtime.h>
#include <math.h>

#define S_LEN 2048
#define DMODEL 1024
#define NH 16
#define DEPTH 64
#define BATCH 2
#define MTOT (BATCH * S_LEN) // 4096

typedef __attribute__((ext_vector_type(8))) short short8;
typedef __attribute__((ext_vector_type(4))) short short4v;
typedef __attribute__((ext_vector_type(4))) float floatx4;

typedef const __attribute__((address_space(1))) unsigned gas_u32;
typedef __attribute__((address_space(3))) unsigned las_u32;

__device__ __forceinline__ short f2bf(float f) {
    union { float f; unsigned u; } v; v.f = f;
    unsigned r = v.u + 0x7fffu + ((v.u >> 16) & 1u);
    return (short)(r >> 16);
}

// Pack two fp32 -> two bf16 in one dword, round-half-up (+0x8000, truncate),
// paired via one v_perm_b32. Valid for finite non-NaN inputs (P in [0,1]).
__device__ __forceinline__ unsigned packbf2(float lo, float hi) {
    union { float f; unsigned u; } a, b;
    a.f = lo; b.f = hi;
    return __builtin_amdgcn_perm(b.u + 0x8000u, a.u + 0x8000u, 0x07060302u);
}

__device__ __forceinline__ floatx4 mfma16(short8 a, short8 b, floatx4 c) {
    return __builtin_amdgcn_mfma_f32_16x16x32_bf16(a, b, c, 0, 0, 0);
}

// K=16 bf16 MFMA: A/B are 4 bf16 per lane (2 VGPRs). A: row=lane&15, k=(lane>>4)*4+e.
#if __has_builtin(__builtin_amdgcn_mfma_f32_16x16x16bf16_1k)
__device__ __forceinline__ floatx4 mfma16k16(short4v a, short4v b, floatx4 c) {
    return __builtin_amdgcn_mfma_f32_16x16x16bf16_1k(a, b, c, 0, 0, 0);
}
#else
__device__ __forceinline__ floatx4 mfma16k16(short4v a, short4v b, floatx4 c) {
    asm volatile("v_mfma_f32_16x16x16_bf16 %0, %1, %2, %0\n\ts_nop 7\n\ts_nop 7"
                 : "+v"(c) : "v"(a), "v"(b));
    return c;
}
#endif

// ---------------- convert x: fp32 -> bf16 ----------------
__global__ __launch_bounds__(256) void convert_x_kernel(const float* __restrict__ x,
                                                        short* __restrict__ xb) {
    int i = (blockIdx.x * 256 + threadIdx.x) * 4;
    float4 v = *(const float4*)(x + i);
    short4v o;
    o.x = f2bf(v.x); o.y = f2bf(v.y); o.z = f2bf(v.z); o.w = f2bf(v.w);
    *(short4v*)(xb + i) = o;
}

// ---------------- transpose+convert weights: (K,N) fp32 -> (N,K) bf16 ----------------
__global__ __launch_bounds__(256) void wt_kernel(const float* __restrict__ w0, const float* __restrict__ w1,
                                                 const float* __restrict__ w2, const float* __restrict__ w3,
                                                 short* __restrict__ o0, short* __restrict__ o1,
                                                 short* __restrict__ o2, short* __restrict__ o3) {
    const float* src; short* dst;
    switch (blockIdx.z) {
        case 0: src = w0; dst = o0; break;
        case 1: src = w1; dst = o1; break;
        case 2: src = w2; dst = o2; break;
        default: src = w3; dst = o3; break;
    }
    __shared__ float tile[32][33];
    int tx = threadIdx.x, ty = threadIdx.y;
    int c = blockIdx.x * 32 + tx;
    int r0 = blockIdx.y * 32;
#pragma unroll
    for (int i = 0; i < 4; i++)
        tile[ty + i * 8][tx] = src[(size_t)(r0 + ty + i * 8) * DMODEL + c];
    __syncthreads();
    int co = blockIdx.y * 32 + tx;
    int ro = blockIdx.x * 32;
#pragma unroll
    for (int i = 0; i < 4; i++)
        dst[(size_t)(ro + ty + i * 8) * DMODEL + co] = f2bf(tile[tx][ty + i * 8]);
}

// ---------------- GEMM v2: global_load_lds staged, XOR-swizzled, double-buffered ----------------
__device__ __forceinline__ void stage_tile(const short* __restrict__ src, int row0, int k0,
                                           short* dstLds, int tid) {
#pragma unroll
    for (int s = 0; s < 4; s++) {
        const int p = s * 4096 + tid * 16;           // linear LDS byte position
        const int q = p ^ (((p >> 7) & 7) << 4);     // inverse-swizzled tile byte
        const char* srcp = (const char*)src + (size_t)(row0 + (q >> 7)) * (DMODEL * 2)
                         + k0 * 2 + (q & 127);
        __builtin_amdgcn_global_load_lds((gas_u32*)srcp,
                                         (las_u32*)((char*)dstLds + p), 16, 0, 0);
    }
}

__device__ __forceinline__ void gemm_core(const short* __restrict__ A,
                                          const short* __restrict__ Bt,
                                          int m0, int n0,
                                          short* Ab0, short* Ab1, short* Bb0, short* Bb1,
                                          floatx4 acc[4][4]) {
    const int tid = threadIdx.x;
    const int lane = tid & 63;
    const int w = tid >> 6;
    const int wr = w >> 1, wc = w & 1;
    const int l15 = lane & 15, lhi = lane >> 4;
    const int swz = (l15 & 7) << 4;

    stage_tile(A, m0, 0, Ab0, tid);
    stage_tile(Bt, n0, 0, Bb0, tid);
    asm volatile("s_waitcnt vmcnt(0)" ::: "memory");
    __syncthreads();

    for (int ks = 0; ks < 16; ks++) {
        const char* Ac = (const char*)((ks & 1) ? Ab1 : Ab0);
        const char* Bc = (const char*)((ks & 1) ? Bb1 : Bb0);
        if (ks < 15) {
            stage_tile(A, m0, (ks + 1) * 64, (ks & 1) ? Ab0 : Ab1, tid);
            stage_tile(Bt, n0, (ks + 1) * 64, (ks & 1) ? Bb0 : Bb1, tid);
        }
#pragma unroll
        for (int kkb = 0; kkb < 128; kkb += 64) {   // byte offset of 32-element K-slice
            short8 af[4], bf[4];
#pragma unroll
            for (int i = 0; i < 4; i++) {
                int row = wr * 64 + i * 16 + l15;
                af[i] = *(const short8*)(Ac + ((row * 128 + kkb + lhi * 16) ^ swz));
            }
#pragma unroll
            for (int j = 0; j < 4; j++) {
                int row = wc * 64 + j * 16 + l15;
                bf[j] = *(const short8*)(Bc + ((row * 128 + kkb + lhi * 16) ^ swz));
            }
#pragma unroll
            for (int i = 0; i < 4; i++)
#pragma unroll
                for (int j = 0; j < 4; j++)
                    acc[i][j] = mfma16(af[i], bf[j], acc[i][j]);
        }
        asm volatile("s_waitcnt vmcnt(0)" ::: "memory");
        __syncthreads();
    }
}

// ---------------- QKV GEMM: out layouts per-head; V transposed; Q pre-scaled ----------------
__global__ __launch_bounds__(256) void gemm_qkv(const short* __restrict__ A,
                                                const short* __restrict__ wq, const short* __restrict__ wk,
                                                const short* __restrict__ wv,
                                                const float* __restrict__ bq, const float* __restrict__ bk,
                                                const float* __restrict__ bv,
                                                short* __restrict__ qh, short* __restrict__ kh,
                                                short* __restrict__ vt) {
    __shared__ __align__(16) short Ab[2][8192];
    __shared__ __align__(16) short Bb[2][8192];
    const int mode = blockIdx.z;
    const short* Bt = (mode == 0) ? wq : (mode == 1) ? wk : wv;
    const float* bias = (mode == 0) ? bq : (mode == 1) ? bk : bv;

    floatx4 acc[4][4];
    floatx4 z = {0.f, 0.f, 0.f, 0.f};
#pragma unroll
    for (int i = 0; i < 4; i++)
#pragma unroll
        for (int j = 0; j < 4; j++) acc[i][j] = z;

    const int m0 = blockIdx.y * 128, n0 = blockIdx.x * 128;
    gemm_core(A, Bt, m0, n0, Ab[0], Ab[1], Bb[0], Bb[1], acc);

    const int lane = threadIdx.x & 63;
    const int w = threadIdx.x >> 6;
    const int wr = w >> 1, wc = w & 1;
    const int l15 = lane & 15, lhi = lane >> 4;
    const float qscale = (mode == 0) ? 0.125f : 1.0f;  // fold 1/sqrt(depth) into Q
#pragma unroll
    for (int i = 0; i < 4; i++) {
#pragma unroll
        for (int j = 0; j < 4; j++) {
            int n = n0 + wc * 64 + j * 16 + l15;
            float bv_ = bias[n];
            int h = n >> 6, d = n & 63;
            int mbase = m0 + wr * 64 + i * 16 + (lhi << 2);
#pragma unroll
            for (int r = 0; r < 4; r++) {
                int m = mbase + r;
                int b = m >> 11, s = m & 2047;
                short val = f2bf((acc[i][j][r] + bv_) * qscale);
                if (mode == 0)
                    qh[((size_t)(b * NH + h) * S_LEN + s) * DEPTH + d] = val;
                else if (mode == 1)
                    kh[((size_t)(b * NH + h) * S_LEN + s) * DEPTH + d] = val;
                else
                    vt[((size_t)(b * NH + h) * DEPTH + d) * S_LEN + s] = val;
            }
        }
    }
}

// ---------------- output projection GEMM: fp32 out ----------------
__global__ __launch_bounds__(256) void gemm_out(const short* __restrict__ A,
                                                const short* __restrict__ Bt,
                                                const float* __restrict__ bias,
                                                float* __restrict__ out) {
    __shared__ __align__(16) short Ab[2][8192];
    __shared__ __align__(16) short Bb[2][8192];
    floatx4 acc[4][4];
    floatx4 z = {0.f, 0.f, 0.f, 0.f};
#pragma unroll
    for (int i = 0; i < 4; i++)
#pragma unroll
        for (int j = 0; j < 4; j++) acc[i][j] = z;

    const int m0 = blockIdx.y * 128, n0 = blockIdx.x * 128;
    gemm_core(A, Bt, m0, n0, Ab[0], Ab[1], Bb[0], Bb[1], acc);

    const int lane = threadIdx.x & 63;
    const int w = threadIdx.x >> 6;
    const int wr = w >> 1, wc = w & 1;
    const int l15 = lane & 15, lhi = lane >> 4;
#pragma unroll
    for (int i = 0; i < 4; i++) {
#pragma unroll
        for (int j = 0; j < 4; j++) {
            int n = n0 + wc * 64 + j * 16 + l15;
            float bv_ = bias[n];
            int mbase = m0 + wr * 64 + i * 16 + (lhi << 2);
#pragma unroll
            for (int r = 0; r < 4; r++) {
                int m = mbase + r;
                out[(size_t)m * DMODEL + n] = acc[i][j][r] + bv_;
            }
        }
    }
}

// ---------------- flash attention v12: v11 + complementary y->chunk remap ----------------
// Same 512-block / 2-per-CU / XCD-local structure as rounds 12-13. Single change:
// y->chunk map [15,13,11,9,7,5,3,1,0,2,4,6,8,10,12,14] makes blocks y and y+8
// (co-resident under mod-256 round-robin block->CU assignment) have chunk sums = 15
// -> every CU processes exactly 34 key-tiles (was 20..48, wall set by the 48s).
// Non-inferior if assignment is consecutive-pairs (worst case unchanged at 64).
__constant__ int YCHUNK[16] = {15, 13, 11, 9, 7, 5, 3, 1, 0, 2, 4, 6, 8, 10, 12, 14};

__device__ __forceinline__ void stage_kv(const short* __restrict__ kb_j0,  // kb + j0*DEPTH
                                         const short* __restrict__ vb, int j0,
                                         short* kt, short* vt_, int wid, int lane) {
#pragma unroll
    for (int s = 0; s < 2; s++) {
        const int seg = (s * 4 + wid) * 1024;        // byte segment of the 8KB tile
        const int p = seg + lane * 16;               // linear LDS byte position
        const int q = p ^ (((p >> 7) & 7) << 4);     // inverse-swizzled source offset
        __builtin_amdgcn_global_load_lds((gas_u32*)((const char*)kb_j0 + q),
                                         (las_u32*)((char*)kt + seg), 16, 0, 0);
        const char* vsrc = (const char*)vb + (size_t)(q >> 7) * (S_LEN * 2) + j0 * 2 + (q & 127);
        __builtin_amdgcn_global_load_lds((gas_u32*)vsrc,
                                         (las_u32*)((char*)vt_ + seg), 16, 0, 0);
    }
}

__global__ __launch_bounds__(256, 2) void attn_kernel(const short* __restrict__ qh,
                                                      const short* __restrict__ kh,
                                                      const short* __restrict__ vt,
                                                      const float* __restrict__ pm,
                                                      short* __restrict__ ao) {
    __shared__ short kbuf[2][4096];
    __shared__ short vbuf[2][4096];
    const int lane = threadIdx.x & 63;
    const int wid = threadIdx.x >> 6;  // 0..3
    const int bh = blockIdx.x;         // bh fastest -> same-head blocks share an XCD
    const int chunk = YCHUNK[blockIdx.y];  // complementary pairing across y and y+8
    const int b = bh >> 4, h = bh & 15;
    const short* qbp = qh + (size_t)bh * S_LEN * DEPTH;
    const short* kb = kh + (size_t)bh * S_LEN * DEPTH;
    const short* vb = vt + (size_t)bh * DEPTH * S_LEN;
    const float* pmb = pm + b * S_LEN;
    const int l15 = lane & 15, lhi = lane >> 4;
    const int swz = (l15 & 7) << 4;

    const int qwb = chunk * 128 + wid * 32;

    short8 qf[2][2];
#pragma unroll
    for (int qg = 0; qg < 2; qg++)
#pragma unroll
        for (int c = 0; c < 2; c++)
            qf[qg][c] = *(const short8*)(qbp + (size_t)(qwb + qg * 16 + l15) * DEPTH + c * 32 + lhi * 8);

    float m_r[2] = {-1e30f, -1e30f};
    float l_part[2] = {0.f, 0.f};
    floatx4 oacc[2][4];
    floatx4 z = {0.f, 0.f, 0.f, 0.f};
#pragma unroll
    for (int qg = 0; qg < 2; qg++)
#pragma unroll
        for (int dt = 0; dt < 4; dt++) oacc[qg][dt] = z;

    const int NT = 2 * chunk + 2;  // key tiles 0 .. chunk*128+64
    stage_kv(kb, vb, 0, kbuf[0], vbuf[0], wid, lane);
    __syncthreads();

    for (int t = 0; t < NT; t++) {
        const int cur = t & 1;
        if (t + 1 < NT)
            stage_kv(kb + (size_t)(t + 1) * 64 * DEPTH, vb, (t + 1) * 64,
                     kbuf[cur ^ 1], vbuf[cur ^ 1], wid, lane);
        const int j0 = t * 64;
        if (j0 <= qwb + 31) {  // wave-uniform: skip fully-masked tiles (barriers still hit)
            const short* kt = kbuf[cur];
            const short* vtile = vbuf[cur];
            short8 kf[4][2];
#pragma unroll
            for (int tt = 0; tt < 4; tt++)
#pragma unroll
                for (int c = 0; c < 2; c++) {
                    int off = (((tt * 16 + l15) * 128) + c * 64 + lhi * 16) ^ swz;
                    kf[tt][c] = *(const short8*)((const char*)kt + off);
                }
            floatx4 sacc[2][4];
#pragma unroll
            for (int qg = 0; qg < 2; qg++)
#pragma unroll
                for (int tt = 0; tt < 4; tt++) sacc[qg][tt] = z;
#pragma unroll
            for (int tt = 0; tt < 4; tt++)
#pragma unroll
                for (int c = 0; c < 2; c++) {
                    sacc[0][tt] = mfma16(kf[tt][c], qf[0][c], sacc[0][tt]);
                    sacc[1][tt] = mfma16(kf[tt][c], qf[1][c], sacc[1][tt]);
                }
            short4v vf[4][4];
#pragma unroll
            for (int tt = 0; tt < 4; tt++)
#pragma unroll
                for (int dt = 0; dt < 4; dt++) {
                    int off = (((dt * 16 + l15) * 128) + tt * 32 + lhi * 8) ^ swz;
                    vf[tt][dt] = *(const short4v*)((const char*)vtile + off);
                }
            float pd[16];
#pragma unroll
            for (int tt = 0; tt < 4; tt++) {
                float4 pmv = *(const float4*)(pmb + j0 + tt * 16 + lhi * 4);
                pd[tt * 4 + 0] = (1.f - pmv.x) * -1e9f;
                pd[tt * 4 + 1] = (1.f - pmv.y) * -1e9f;
                pd[tt * 4 + 2] = (1.f - pmv.z) * -1e9f;
                pd[tt * 4 + 3] = (1.f - pmv.w) * -1e9f;
            }
#pragma unroll
            for (int qg = 0; qg < 2; qg++) {
                const int q = qwb + qg * 16 + l15;
                const bool domask = (j0 + 63 > qwb + qg * 16);
                float mx = -1e30f;
#pragma unroll
                for (int tt = 0; tt < 4; tt++)
#pragma unroll
                    for (int r = 0; r < 4; r++) {
                        float v = sacc[qg][tt][r] + pd[tt * 4 + r];
                        if (domask) {
                            int key = j0 + tt * 16 + lhi * 4 + r;
                            v = (key > q) ? -1e30f : v;
                        }
                        sacc[qg][tt][r] = v;
                        mx = fmaxf(mx, v);
                    }
                mx = fmaxf(mx, __shfl_xor(mx, 16, 64));
                mx = fmaxf(mx, __shfl_xor(mx, 32, 64));
                float mnew = fmaxf(m_r[qg], mx);
                float sf = __expf(m_r[qg] - mnew);
                m_r[qg] = mnew;
                l_part[qg] *= sf;
#pragma unroll
                for (int r = 0; r < 4; r++) {
                    float sfr = __shfl(sf, lhi * 4 + r, 64);
#pragma unroll
                    for (int dt = 0; dt < 4; dt++) oacc[qg][dt][r] *= sfr;
                }
#pragma unroll
                for (int tt = 0; tt < 4; tt++) {
                    float p0 = __expf(sacc[qg][tt][0] - m_r[qg]);
                    float p1 = __expf(sacc[qg][tt][1] - m_r[qg]);
                    float p2 = __expf(sacc[qg][tt][2] - m_r[qg]);
                    float p3 = __expf(sacc[qg][tt][3] - m_r[qg]);
                    l_part[qg] += (p0 + p1) + (p2 + p3);
                    union { unsigned u[2]; short4v s; } cv;
                    cv.u[0] = packbf2(p0, p1);
                    cv.u[1] = packbf2(p2, p3);
#pragma unroll
                    for (int dt = 0; dt < 4; dt++)
                        oacc[qg][dt] = mfma16k16(cv.s, vf[tt][dt], oacc[qg][dt]);
                }
            }
        }
        asm volatile("s_waitcnt vmcnt(0)" ::: "memory");
        __syncthreads();
    }

    // ---- epilogue: reduce per-lane partial sums once ----
#pragma unroll
    for (int qg = 0; qg < 2; qg++) {
        float lsum = l_part[qg];
        lsum += __shfl_xor(lsum, 16, 64);
        lsum += __shfl_xor(lsum, 32, 64);
        float rinv[4];
#pragma unroll
        for (int r = 0; r < 4; r++)
            rinv[r] = 1.0f / __shfl(lsum, lhi * 4 + r, 64);
#pragma unroll
        for (int dt = 0; dt < 4; dt++) {
            int d = dt * 16 + l15;
#pragma unroll
            for (int r = 0; r < 4; r++) {
                int row = qwb + qg * 16 + lhi * 4 + r;
                float o = oacc[qg][dt][r] * rinv[r];
                ao[((size_t)(b * S_LEN) + row) * DMODEL + h * DEPTH + d] = f2bf(o);
            }
        }
    }
}

extern "C" void kernel_launch(void* const* d_in, const int* in_sizes, int n_in,
                              void* d_out, int out_size, void* d_ws, size_t ws_size,
                              hipStream_t stream) {
    const float* x    = (const float*)d_in[0];
    const float* pm   = (const float*)d_in[1];
    const float* wq_w = (const float*)d_in[2];
    const float* wq_b = (const float*)d_in[3];
    const float* wk_w = (const float*)d_in[4];
    const float* wk_b = (const float*)d_in[5];
    const float* wv_w = (const float*)d_in[6];
    const float* wv_b = (const float*)d_in[7];
    const float* wo_w = (const float*)d_in[8];
    const float* wo_b = (const float*)d_in[9];
    float* out = (float*)d_out;

    char* ws = (char*)d_ws;
    const size_t MB = 1024 * 1024;
    short* xb  = (short*)(ws);            // 8 MB : x bf16 (4096x1024)
    short* wqb = (short*)(ws + 8 * MB);   // 2 MB : wq^T bf16
    short* wkb = (short*)(ws + 10 * MB);
    short* wvb = (short*)(ws + 12 * MB);
    short* wob = (short*)(ws + 14 * MB);
    short* qh  = (short*)(ws + 16 * MB);  // 8 MB : Q (B,H,S,depth) bf16, pre-scaled by 0.125
    short* kh  = (short*)(ws + 24 * MB);  // 8 MB : K (B,H,S,depth) bf16
    short* vt  = (short*)(ws + 32 * MB);  // 8 MB : V^T (B,H,depth,S) bf16
    short* ao  = (short*)(ws + 40 * MB);  // 8 MB : attn out (B,S,D) bf16

    convert_x_kernel<<<4096, 256, 0, stream>>>(x, xb);
    wt_kernel<<<dim3(32, 32, 4), dim3(32, 8), 0, stream>>>(wq_w, wk_w, wv_w, wo_w,
                                                           wqb, wkb, wvb, wob);
    gemm_qkv<<<dim3(8, 32, 3), 256, 0, stream>>>(xb, wqb, wkb, wvb, wq_b, wk_b, wv_b,
                                                 qh, kh, vt);
    attn_kernel<<<dim3(32, 16), 256, 0, stream>>>(qh, kh, vt, pm, ao);
    gemm_out<<<dim3(8, 32), 256, 0, stream>>>(ao, wob, wo_b, out);
}